// Round 2
// baseline (5464.083 us; speedup 1.0000x reference)
//
#include <hip/hip_runtime.h>

#define ANG 9
#define HH 96
#define BB 2
#define PLANE_F (81*HH*HH)  // 746496 per channel (81 views x 96x96)
#define PLANE_A (HH*HH)     // 9216

// ===== feature conv0: 1->7, reads SAI views directly from x, per-view 3x3 pad=1 =====
__global__ __launch_bounds__(256) void k_featconv0(const float* __restrict__ x,
    const float* __restrict__ w, float* __restrict__ out) {
  int t = blockIdx.x * 256 + threadIdx.x;           // BB*81*9216 = 1492992 exact
  int p = t % PLANE_A; int r = t / PLANE_A; int uv = r % 81; int b = r / 81;
  int i = p / HH, j = p % HH;
  int u = uv / 9, v = uv % 9;
  const float* ip = x + (size_t)b * PLANE_F + (u * HH) * 864 + v * HH;
  float acc[7];
  #pragma unroll
  for (int o = 0; o < 7; o++) acc[o] = 0.f;
  #pragma unroll
  for (int ky = 0; ky < 3; ky++) {
    int ii = i + ky - 1;
    if ((unsigned)ii >= (unsigned)HH) continue;
    #pragma unroll
    for (int kx = 0; kx < 3; kx++) {
      int jj = j + kx - 1;
      if ((unsigned)jj >= (unsigned)HH) continue;
      float val = ip[ii * 864 + jj];
      #pragma unroll
      for (int o = 0; o < 7; o++)
        acc[o] = fmaf(w[o * 9 + ky * 3 + kx], val, acc[o]);
    }
  }
  #pragma unroll
  for (int o = 0; o < 7; o++)
    out[((size_t)(b * 7 + o)) * PLANE_F + uv * PLANE_A + p] = acc[o];
}

// ===== feature conv: 7->7 per-view 3x3 pad=1, fused input BN+ReLU =====
__global__ __launch_bounds__(256) void k_featconv(const float* __restrict__ in,
    const float* __restrict__ w, const float* __restrict__ sc, const float* __restrict__ sh,
    float* __restrict__ out) {
  int t = blockIdx.x * 256 + threadIdx.x;
  int p = t % PLANE_A; int r = t / PLANE_A; int uv = r % 81; int b = r / 81;
  int i = p / HH, j = p % HH;
  float acc[7];
  #pragma unroll
  for (int o = 0; o < 7; o++) acc[o] = 0.f;
  #pragma unroll
  for (int c = 0; c < 7; c++) {
    const float* ip = in + ((size_t)(b * 7 + c)) * PLANE_F + uv * PLANE_A;
    float s = sc[c], h2 = sh[c];
    #pragma unroll
    for (int ky = 0; ky < 3; ky++) {
      int ii = i + ky - 1;
      if ((unsigned)ii >= (unsigned)HH) continue;
      #pragma unroll
      for (int kx = 0; kx < 3; kx++) {
        int jj = j + kx - 1;
        if ((unsigned)jj >= (unsigned)HH) continue;
        float val = fmaxf(fmaf(ip[ii * HH + jj], s, h2), 0.f);
        #pragma unroll
        for (int o = 0; o < 7; o++)
          acc[o] = fmaf(w[(o * 7 + c) * 9 + ky * 3 + kx], val, acc[o]);
      }
    }
  }
  #pragma unroll
  for (int o = 0; o < 7; o++)
    out[((size_t)(b * 7 + o)) * PLANE_F + uv * PLANE_A + p] = acc[o];
}

// ===== batch stats (big maps): stage 1 partial sums =====
__global__ __launch_bounds__(256) void k_stats_partial(const float* __restrict__ in,
    float* __restrict__ part, int C, int plane, int NB) {
  int c = blockIdx.x / NB, blk = blockIdx.x % NB;
  int tid = threadIdx.x;
  int N = BB * plane;
  float s = 0.f, q = 0.f;
  for (int i = blk * 256 + tid; i < N; i += NB * 256) {
    int b = i / plane, p = i - b * plane;
    float v = in[((size_t)(b * C + c)) * plane + p];
    s += v; q += v * v;
  }
  __shared__ float ss[256], qq[256];
  ss[tid] = s; qq[tid] = q;
  __syncthreads();
  for (int st = 128; st > 0; st >>= 1) {
    if (tid < st) { ss[tid] += ss[tid + st]; qq[tid] += qq[tid + st]; }
    __syncthreads();
  }
  if (tid == 0) { part[(c * NB + blk) * 2] = ss[0]; part[(c * NB + blk) * 2 + 1] = qq[0]; }
}

__global__ void k_stats_final(const float* __restrict__ part, const float* __restrict__ g,
    const float* __restrict__ bb, float* __restrict__ sc, float* __restrict__ sh,
    int C, int NB, float invN) {
  int c = blockIdx.x * 64 + threadIdx.x;
  if (c >= C) return;
  float s = 0.f, q = 0.f;
  for (int i = 0; i < NB; i++) { s += part[(c * NB + i) * 2]; q += part[(c * NB + i) * 2 + 1]; }
  float mean = s * invN;
  float var = fmaxf(q * invN - mean * mean, 0.f);
  float scale = g[c] / sqrtf(var + 1e-5f);
  sc[c] = scale; sh[c] = bb[c] - mean * scale;
}

// ===== batch stats (96x96 maps): one block per channel =====
__global__ __launch_bounds__(256) void k_stats_small(const float* __restrict__ in,
    const float* __restrict__ g, const float* __restrict__ bb,
    float* __restrict__ sc, float* __restrict__ sh, int C) {
  int c = blockIdx.x, tid = threadIdx.x;
  const int N = BB * PLANE_A;
  float s = 0.f, q = 0.f;
  for (int i = tid; i < N; i += 256) {
    int b = i / PLANE_A, p = i - b * PLANE_A;
    float v = in[((size_t)(b * C + c)) * PLANE_A + p];
    s += v; q += v * v;
  }
  __shared__ float ss[256], qq[256];
  ss[tid] = s; qq[tid] = q;
  __syncthreads();
  for (int st = 128; st > 0; st >>= 1) {
    if (tid < st) { ss[tid] += ss[tid + st]; qq[tid] += qq[tid + st]; }
    __syncthreads();
  }
  if (tid == 0) {
    float mean = ss[0] / (float)N;
    float var = fmaxf(qq[0] / (float)N - mean * mean, 0.f);
    float scale = g[c] / sqrtf(var + 1e-5f);
    sc[c] = scale; sh[c] = bb[c] - mean * scale;
  }
}

// ===== BuildCost in SAI layout: per-view shifted sampling, 16 FMA per load =====
// grid (36, 9, 2), block 256. F sample for group g (d=g-4), view (u,v):
//   i' = i + d*(4-u), j' = j + d*(4-v); weight index (8-u,8-v) if d>0 else (u,v).
__global__ __launch_bounds__(256) void k_buildcost(const float* __restrict__ F,
    const float* __restrict__ sc, const float* __restrict__ sh,
    const float* __restrict__ w, float* __restrict__ cv) {
  __shared__ float wl[9072];                        // [c*81 + u*9 + v][o16] raw order
  __shared__ float scl[7], shl[7];
  int g = blockIdx.y, b = blockIdx.z, tid = threadIdx.x;
  for (int k = tid; k < 9072; k += 256) {
    int o = k & 15; int r = k >> 4;                 // r = c*81 + u*9 + v
    wl[k] = w[(g * 16 + o) * 567 + r];
  }
  if (tid < 7) { scl[tid] = sc[tid]; shl[tid] = sh[tid]; }
  __syncthreads();
  int d = g - 4;
  bool flip = d > 0;
  int p = blockIdx.x * 256 + tid;
  int i = p / HH, j = p % HH;
  float acc[16];
  #pragma unroll
  for (int o = 0; o < 16; o++) acc[o] = 0.f;
  for (int c = 0; c < 7; c++) {
    const float* Fc = F + ((size_t)(b * 7 + c)) * PLANE_F;
    float s = scl[c], h2 = shl[c];
    #pragma unroll
    for (int u = 0; u < 9; u++) {
      int ii = i + d * (4 - u);
      bool okI = (unsigned)ii < (unsigned)HH;
      int uw = flip ? 8 - u : u;
      const float* Frow = Fc + (u * 9) * PLANE_A + ii * HH;
      const float* wu = &wl[(c * 81 + uw * 9) * 16];
      #pragma unroll
      for (int v = 0; v < 9; v++) {
        int jj = j + d * (4 - v);
        float a = 0.f;
        if (okI && (unsigned)jj < (unsigned)HH)
          a = fmaxf(fmaf(Frow[v * PLANE_A + jj], s, h2), 0.f);
        int vw = flip ? 8 - v : v;
        const float* wv = wu + vw * 16;
        #pragma unroll
        for (int o = 0; o < 16; o++) acc[o] = fmaf(wv[o], a, acc[o]);
      }
    }
  }
  size_t cvb = ((size_t)(b * 144 + g * 16)) * PLANE_A + p;
  #pragma unroll
  for (int o = 0; o < 16; o++) cv[cvb + o * PLANE_A] = acc[o];
}

// ===== depthwise 3x3 pad=1, optional fused input BN+ReLU =====
template<bool AFF>
__global__ __launch_bounds__(256) void k_dwconv(const float* __restrict__ in,
    const float* __restrict__ w, const float* __restrict__ isc, const float* __restrict__ ish,
    float* __restrict__ out, int C) {
  int t = blockIdx.x * 256 + threadIdx.x;
  int j = t % HH; int r = t / HH; int i = r % HH; r /= HH; int c = r % C; int b = r / C;
  float s  = AFF ? isc[c] : 1.f;
  float h2 = AFF ? ish[c] : 0.f;
  const float* ip = in + ((size_t)(b * C + c)) * PLANE_A;
  float acc = 0.f;
  #pragma unroll
  for (int ky = 0; ky < 3; ky++) {
    int ii = i + ky - 1;
    if ((unsigned)ii >= (unsigned)HH) continue;
    #pragma unroll
    for (int kx = 0; kx < 3; kx++) {
      int jj = j + kx - 1;
      if ((unsigned)jj >= (unsigned)HH) continue;
      float v = ip[ii * HH + jj];
      if (AFF) v = fmaxf(fmaf(v, s, h2), 0.f);
      acc = fmaf(w[c * 9 + ky * 3 + kx], v, acc);
    }
  }
  out[t] = acc;
}

// ===== pointwise conv (GEMM), fused input BN+ReLU during staging =====
#define PW_TP 64
#define PW_TO 192
#define PW_KC 36
template<int K>
__global__ __launch_bounds__(256) void k_pwconv(const float* __restrict__ in,
    const float* __restrict__ sc, const float* __restrict__ sh,
    const float* __restrict__ w, float* __restrict__ out, int O) {
  __shared__ float xs[PW_KC][PW_TP];
  __shared__ float ws[PW_KC][PW_TO];
  __shared__ float scl[K], shl[K];
  int tid = threadIdx.x;
  for (int c = tid; c < K; c += 256) { scl[c] = sc[c]; shl[c] = sh[c]; }
  __syncthreads();
  int tile = blockIdx.x;
  int p0 = tile * PW_TP;
  int b = p0 / PLANE_A;
  int pp0 = p0 - b * PLANE_A;
  int tx = tid % 16, ty = tid / 16;
  float acc[4][12];
  #pragma unroll
  for (int q = 0; q < 4; q++)
    #pragma unroll
    for (int o = 0; o < 12; o++) acc[q][o] = 0.f;
  for (int k0 = 0; k0 < K; k0 += PW_KC) {
    for (int idx = tid; idx < PW_KC * PW_TP; idx += 256) {
      int kk = idx / PW_TP, p = idx - kk * PW_TP;
      int c = k0 + kk;
      float v = in[((size_t)(b * K + c)) * PLANE_A + pp0 + p];
      xs[kk][p] = fmaxf(fmaf(v, scl[c], shl[c]), 0.f);
    }
    for (int idx = tid; idx < PW_KC * PW_TO; idx += 256) {
      int kk = idx / PW_TO, o = idx - kk * PW_TO;
      ws[kk][o] = (o < O) ? w[o * K + k0 + kk] : 0.f;
    }
    __syncthreads();
    #pragma unroll 4
    for (int kk = 0; kk < PW_KC; kk++) {
      float x0 = xs[kk][tx * 4 + 0], x1 = xs[kk][tx * 4 + 1];
      float x2 = xs[kk][tx * 4 + 2], x3 = xs[kk][tx * 4 + 3];
      const float* wr = &ws[kk][ty * 12];
      #pragma unroll
      for (int o = 0; o < 12; o++) {
        float wv = wr[o];
        acc[0][o] = fmaf(x0, wv, acc[0][o]);
        acc[1][o] = fmaf(x1, wv, acc[1][o]);
        acc[2][o] = fmaf(x2, wv, acc[2][o]);
        acc[3][o] = fmaf(x3, wv, acc[3][o]);
      }
    }
    __syncthreads();
  }
  #pragma unroll
  for (int o = 0; o < 12; o++) {
    int oo = ty * 12 + o;
    if (oo < O) {
      float* op = out + ((size_t)(b * O + oo)) * PLANE_A + pp0 + tx * 4;
      op[0] = acc[0][o]; op[1] = acc[1][o]; op[2] = acc[2][o]; op[3] = acc[3][o];
    }
  }
}

// ===== final: 1x1 conv 180->9 + softmax + disparity expectation =====
__global__ __launch_bounds__(256) void k_final(const float* __restrict__ in,
    const float* __restrict__ sc, const float* __restrict__ sh,
    const float* __restrict__ w, float* __restrict__ out) {
  __shared__ float wl[9 * 180];
  __shared__ float scl[180], shl[180];
  int tid = threadIdx.x;
  for (int k = tid; k < 1620; k += 256) wl[k] = w[k];
  for (int c = tid; c < 180; c += 256) { scl[c] = sc[c]; shl[c] = sh[c]; }
  __syncthreads();
  int t = blockIdx.x * 256 + tid;
  int b = t / PLANE_A, p = t - b * PLANE_A;
  float acc[9];
  #pragma unroll
  for (int o = 0; o < 9; o++) acc[o] = 0.f;
  for (int c = 0; c < 180; c++) {
    float v = fmaxf(fmaf(in[((size_t)(b * 180 + c)) * PLANE_A + p], scl[c], shl[c]), 0.f);
    #pragma unroll
    for (int o = 0; o < 9; o++) acc[o] = fmaf(wl[o * 180 + c], v, acc[o]);
  }
  float m = acc[0];
  #pragma unroll
  for (int o = 1; o < 9; o++) m = fmaxf(m, acc[o]);
  float se = 0.f, num = 0.f;
  #pragma unroll
  for (int o = 0; o < 9; o++) {
    float e = expf(acc[o] - m);
    se += e;
    num += (float)(o - 4) * e;
  }
  out[t] = num / se;
}

extern "C" void kernel_launch(void* const* d_in, const int* in_sizes, int n_in,
                              void* d_out, int out_size, void* d_ws, size_t ws_size,
                              hipStream_t stream) {
  const float* x    = (const float*)d_in[0];
  const float* fw0  = (const float*)d_in[1];
  const float* fg0  = (const float*)d_in[2];
  const float* fb0  = (const float*)d_in[3];
  const float* fw   = (const float*)d_in[4];
  const float* fg   = (const float*)d_in[5];
  const float* fb   = (const float*)d_in[6];
  const float* bcw  = (const float*)d_in[7];
  const float* a0dw = (const float*)d_in[8];
  const float* a0dg = (const float*)d_in[9];
  const float* a0db = (const float*)d_in[10];
  const float* a0pw = (const float*)d_in[11];
  const float* a0pg = (const float*)d_in[12];
  const float* a0pb = (const float*)d_in[13];
  const float* amdw = (const float*)d_in[14];
  const float* amdg = (const float*)d_in[15];
  const float* amdb = (const float*)d_in[16];
  const float* ampw = (const float*)d_in[17];
  const float* ampg = (const float*)d_in[18];
  const float* ampb = (const float*)d_in[19];
  const float* ldw  = (const float*)d_in[20];
  const float* ldg  = (const float*)d_in[21];
  const float* ldb  = (const float*)d_in[22];
  const float* lpw  = (const float*)d_in[23];
  float* outp = (float*)d_out;

  float* FA    = (float*)d_ws;
  float* FB    = FA + (size_t)BB * 7 * PLANE_F;
  float* CV    = FB + (size_t)BB * 7 * PLANE_F;
  float* GA    = CV + (size_t)BB * 144 * PLANE_A;
  float* GB    = GA + (size_t)BB * 180 * PLANE_A;
  float* PART  = GB + (size_t)BB * 180 * PLANE_A;
  float* SC    = PART + 180 * 64 * 2;
  float* SH    = SC + 180;

  const int nblk_f = BB * PLANE_F / 256;             // 5832

  // feature extraction in SAI-view layout (MacPI rearrange folded away)
  k_featconv0<<<nblk_f, 256, 0, stream>>>(x, fw0, FA);
  k_stats_partial<<<7 * 64, 256, 0, stream>>>(FA, PART, 7, PLANE_F, 64);
  k_stats_final<<<1, 64, 0, stream>>>(PART, fg0, fb0, SC, SH, 7, 64, 1.0f / (float)(BB * PLANE_F));

  float* cur = FA; float* nxt = FB;
  for (int i = 0; i < 6; i++) {
    k_featconv<<<nblk_f, 256, 0, stream>>>(cur, fw + i * 441, SC, SH, nxt);
    k_stats_partial<<<7 * 64, 256, 0, stream>>>(nxt, PART, 7, PLANE_F, 64);
    k_stats_final<<<1, 64, 0, stream>>>(PART, fg + i * 7, fb + i * 7, SC, SH, 7, 64,
                                        1.0f / (float)(BB * PLANE_F));
    float* tmp = cur; cur = nxt; nxt = tmp;
  }

  // BuildCost (disp_shift folded, SAI sampling)
  k_buildcost<<<dim3(36, 9, 2), 256, 0, stream>>>(cur, SC, SH, bcw, CV);

  // aggregation
  k_dwconv<false><<<BB * 144 * PLANE_A / 256, 256, 0, stream>>>(CV, a0dw, nullptr, nullptr, GA, 144);
  k_stats_small<<<144, 256, 0, stream>>>(GA, a0dg, a0db, SC, SH, 144);
  k_pwconv<144><<<288, 256, 0, stream>>>(GA, SC, SH, a0pw, GB, 180);
  k_stats_small<<<180, 256, 0, stream>>>(GB, a0pg, a0pb, SC, SH, 180);

  for (int m = 0; m < 4; m++) {
    k_dwconv<true><<<BB * 180 * PLANE_A / 256, 256, 0, stream>>>(GB, amdw + m * 1620, SC, SH, GA, 180);
    k_stats_small<<<180, 256, 0, stream>>>(GA, amdg + m * 180, amdb + m * 180, SC, SH, 180);
    k_pwconv<180><<<288, 256, 0, stream>>>(GA, SC, SH, ampw + m * 32400, GB, 180);
    k_stats_small<<<180, 256, 0, stream>>>(GB, ampg + m * 180, ampb + m * 180, SC, SH, 180);
  }

  k_dwconv<true><<<BB * 180 * PLANE_A / 256, 256, 0, stream>>>(GB, ldw, SC, SH, GA, 180);
  k_stats_small<<<180, 256, 0, stream>>>(GA, ldg, ldb, SC, SH, 180);

  k_final<<<72, 256, 0, stream>>>(GA, SC, SH, lpw, outp);
}

// Round 3
// 1848.684 us; speedup vs baseline: 2.9557x; 2.9557x over previous
//
#include <hip/hip_runtime.h>

#define ANG 9
#define HH 96
#define BB 2
#define PLANE_F (81*HH*HH)  // 746496 per channel (81 views x 96x96)
#define PLANE_A (HH*HH)     // 9216

// ===== feature conv0: 1->7, reads SAI views directly from x, per-view 3x3 pad=1 =====
__global__ __launch_bounds__(256) void k_featconv0(const float* __restrict__ x,
    const float* __restrict__ w, float* __restrict__ out) {
  int t = blockIdx.x * 256 + threadIdx.x;           // BB*81*9216 = 1492992 exact
  int p = t % PLANE_A; int r = t / PLANE_A; int uv = r % 81; int b = r / 81;
  int i = p / HH, j = p % HH;
  int u = uv / 9, v = uv % 9;
  const float* ip = x + (size_t)b * PLANE_F + (u * HH) * 864 + v * HH;
  float acc[7];
  #pragma unroll
  for (int o = 0; o < 7; o++) acc[o] = 0.f;
  #pragma unroll
  for (int ky = 0; ky < 3; ky++) {
    int ii = i + ky - 1;
    if ((unsigned)ii >= (unsigned)HH) continue;
    #pragma unroll
    for (int kx = 0; kx < 3; kx++) {
      int jj = j + kx - 1;
      if ((unsigned)jj >= (unsigned)HH) continue;
      float val = ip[ii * 864 + jj];
      #pragma unroll
      for (int o = 0; o < 7; o++)
        acc[o] = fmaf(w[o * 9 + ky * 3 + kx], val, acc[o]);
    }
  }
  #pragma unroll
  for (int o = 0; o < 7; o++)
    out[((size_t)(b * 7 + o)) * PLANE_F + uv * PLANE_A + p] = acc[o];
}

// ===== feature conv: 7->7 per-view 3x3 pad=1, fused input BN+ReLU =====
__global__ __launch_bounds__(256) void k_featconv(const float* __restrict__ in,
    const float* __restrict__ w, const float* __restrict__ sc, const float* __restrict__ sh,
    float* __restrict__ out) {
  int t = blockIdx.x * 256 + threadIdx.x;
  int p = t % PLANE_A; int r = t / PLANE_A; int uv = r % 81; int b = r / 81;
  int i = p / HH, j = p % HH;
  float acc[7];
  #pragma unroll
  for (int o = 0; o < 7; o++) acc[o] = 0.f;
  #pragma unroll
  for (int c = 0; c < 7; c++) {
    const float* ip = in + ((size_t)(b * 7 + c)) * PLANE_F + uv * PLANE_A;
    float s = sc[c], h2 = sh[c];
    #pragma unroll
    for (int ky = 0; ky < 3; ky++) {
      int ii = i + ky - 1;
      if ((unsigned)ii >= (unsigned)HH) continue;
      #pragma unroll
      for (int kx = 0; kx < 3; kx++) {
        int jj = j + kx - 1;
        if ((unsigned)jj >= (unsigned)HH) continue;
        float val = fmaxf(fmaf(ip[ii * HH + jj], s, h2), 0.f);
        #pragma unroll
        for (int o = 0; o < 7; o++)
          acc[o] = fmaf(w[(o * 7 + c) * 9 + ky * 3 + kx], val, acc[o]);
      }
    }
  }
  #pragma unroll
  for (int o = 0; o < 7; o++)
    out[((size_t)(b * 7 + o)) * PLANE_F + uv * PLANE_A + p] = acc[o];
}

// ===== batch stats (big maps): stage 1 partial sums =====
__global__ __launch_bounds__(256) void k_stats_partial(const float* __restrict__ in,
    float* __restrict__ part, int C, int plane, int NB) {
  int c = blockIdx.x / NB, blk = blockIdx.x % NB;
  int tid = threadIdx.x;
  int N = BB * plane;
  float s = 0.f, q = 0.f;
  for (int i = blk * 256 + tid; i < N; i += NB * 256) {
    int b = i / plane, p = i - b * plane;
    float v = in[((size_t)(b * C + c)) * plane + p];
    s += v; q += v * v;
  }
  __shared__ float ss[256], qq[256];
  ss[tid] = s; qq[tid] = q;
  __syncthreads();
  for (int st = 128; st > 0; st >>= 1) {
    if (tid < st) { ss[tid] += ss[tid + st]; qq[tid] += qq[tid + st]; }
    __syncthreads();
  }
  if (tid == 0) { part[(c * NB + blk) * 2] = ss[0]; part[(c * NB + blk) * 2 + 1] = qq[0]; }
}

__global__ void k_stats_final(const float* __restrict__ part, const float* __restrict__ g,
    const float* __restrict__ bb, float* __restrict__ sc, float* __restrict__ sh,
    int C, int NB, float invN) {
  int c = blockIdx.x * 64 + threadIdx.x;
  if (c >= C) return;
  float s = 0.f, q = 0.f;
  for (int i = 0; i < NB; i++) { s += part[(c * NB + i) * 2]; q += part[(c * NB + i) * 2 + 1]; }
  float mean = s * invN;
  float var = fmaxf(q * invN - mean * mean, 0.f);
  float scale = g[c] / sqrtf(var + 1e-5f);
  sc[c] = scale; sh[c] = bb[c] - mean * scale;
}

// ===== batch stats (96x96 maps): one block per channel =====
__global__ __launch_bounds__(256) void k_stats_small(const float* __restrict__ in,
    const float* __restrict__ g, const float* __restrict__ bb,
    float* __restrict__ sc, float* __restrict__ sh, int C) {
  int c = blockIdx.x, tid = threadIdx.x;
  const int N = BB * PLANE_A;
  float s = 0.f, q = 0.f;
  for (int i = tid; i < N; i += 256) {
    int b = i / PLANE_A, p = i - b * PLANE_A;
    float v = in[((size_t)(b * C + c)) * PLANE_A + p];
    s += v; q += v * v;
  }
  __shared__ float ss[256], qq[256];
  ss[tid] = s; qq[tid] = q;
  __syncthreads();
  for (int st = 128; st > 0; st >>= 1) {
    if (tid < st) { ss[tid] += ss[tid + st]; qq[tid] += qq[tid + st]; }
    __syncthreads();
  }
  if (tid == 0) {
    float mean = ss[0] / (float)N;
    float var = fmaxf(qq[0] / (float)N - mean * mean, 0.f);
    float scale = g[c] / sqrtf(var + 1e-5f);
    sc[c] = scale; sh[c] = bb[c] - mean * scale;
  }
}

// ===== BuildCost in SAI layout: per-view shifted sampling =====
// grid (36, 9, 2), block 256. F sample for group g (d=g-4), view (u,v):
//   i' = i + d*(4-u), j' = j + d*(4-v); weight index (8-u,8-v) if d>0 else (u,v).
// Spill-free structure: outer c,u loops NOT unrolled (pragma unroll 1), v-taps
// gathered into vals[9] then 144 FMAs; launch_bounds caps VGPR<=128 (4 blk/CU).
__global__ __launch_bounds__(256, 4) void k_buildcost(const float* __restrict__ F,
    const float* __restrict__ sc, const float* __restrict__ sh,
    const float* __restrict__ w, float* __restrict__ cv) {
  __shared__ float wl[9072];                        // [c*81 + u*9 + v][o16] raw order
  __shared__ float scl[7], shl[7];
  int g = blockIdx.y, b = blockIdx.z, tid = threadIdx.x;
  for (int k = tid; k < 9072; k += 256) {
    int o = k & 15; int r = k >> 4;                 // r = c*81 + u*9 + v
    wl[k] = w[(g * 16 + o) * 567 + r];
  }
  if (tid < 7) { scl[tid] = sc[tid]; shl[tid] = sh[tid]; }
  __syncthreads();
  int d = g - 4;
  bool flip = d > 0;
  int p = blockIdx.x * 256 + tid;
  int i = p / HH, j = p % HH;
  float acc[16];
  #pragma unroll
  for (int o = 0; o < 16; o++) acc[o] = 0.f;
  #pragma unroll 1
  for (int c = 0; c < 7; c++) {
    const float* Fc = F + ((size_t)(b * 7 + c)) * PLANE_F;
    float s = scl[c], h2 = shl[c];
    #pragma unroll 1
    for (int u = 0; u < 9; u++) {
      int ii = i + d * (4 - u);
      bool okI = (unsigned)ii < (unsigned)HH;
      int uw = flip ? 8 - u : u;
      const float* Frow = Fc + (u * 9) * PLANE_A + ii * HH;
      const float* wu = &wl[(c * 81 + uw * 9) * 16];
      float vals[9];
      #pragma unroll
      for (int v = 0; v < 9; v++) {
        int jj = j + d * (4 - v);
        bool ok = okI && ((unsigned)jj < (unsigned)HH);
        vals[v] = ok ? fmaxf(fmaf(Frow[v * PLANE_A + jj], s, h2), 0.f) : 0.f;
      }
      #pragma unroll
      for (int v = 0; v < 9; v++) {
        int vw = flip ? 8 - v : v;
        const float* wv = wu + vw * 16;
        float a = vals[v];
        #pragma unroll
        for (int o = 0; o < 16; o++) acc[o] = fmaf(wv[o], a, acc[o]);
      }
    }
  }
  size_t cvb = ((size_t)(b * 144 + g * 16)) * PLANE_A + p;
  #pragma unroll
  for (int o = 0; o < 16; o++) cv[cvb + o * PLANE_A] = acc[o];
}

// ===== depthwise 3x3 pad=1, optional fused input BN+ReLU =====
template<bool AFF>
__global__ __launch_bounds__(256) void k_dwconv(const float* __restrict__ in,
    const float* __restrict__ w, const float* __restrict__ isc, const float* __restrict__ ish,
    float* __restrict__ out, int C) {
  int t = blockIdx.x * 256 + threadIdx.x;
  int j = t % HH; int r = t / HH; int i = r % HH; r /= HH; int c = r % C; int b = r / C;
  float s  = AFF ? isc[c] : 1.f;
  float h2 = AFF ? ish[c] : 0.f;
  const float* ip = in + ((size_t)(b * C + c)) * PLANE_A;
  float acc = 0.f;
  #pragma unroll
  for (int ky = 0; ky < 3; ky++) {
    int ii = i + ky - 1;
    if ((unsigned)ii >= (unsigned)HH) continue;
    #pragma unroll
    for (int kx = 0; kx < 3; kx++) {
      int jj = j + kx - 1;
      if ((unsigned)jj >= (unsigned)HH) continue;
      float v = ip[ii * HH + jj];
      if (AFF) v = fmaxf(fmaf(v, s, h2), 0.f);
      acc = fmaf(w[c * 9 + ky * 3 + kx], v, acc);
    }
  }
  out[t] = acc;
}

// ===== pointwise conv (GEMM), fused input BN+ReLU during staging =====
#define PW_TP 64
#define PW_TO 192
#define PW_KC 36
template<int K>
__global__ __launch_bounds__(256) void k_pwconv(const float* __restrict__ in,
    const float* __restrict__ sc, const float* __restrict__ sh,
    const float* __restrict__ w, float* __restrict__ out, int O) {
  __shared__ float xs[PW_KC][PW_TP];
  __shared__ float ws[PW_KC][PW_TO];
  __shared__ float scl[K], shl[K];
  int tid = threadIdx.x;
  for (int c = tid; c < K; c += 256) { scl[c] = sc[c]; shl[c] = sh[c]; }
  __syncthreads();
  int tile = blockIdx.x;
  int p0 = tile * PW_TP;
  int b = p0 / PLANE_A;
  int pp0 = p0 - b * PLANE_A;
  int tx = tid % 16, ty = tid / 16;
  float acc[4][12];
  #pragma unroll
  for (int q = 0; q < 4; q++)
    #pragma unroll
    for (int o = 0; o < 12; o++) acc[q][o] = 0.f;
  for (int k0 = 0; k0 < K; k0 += PW_KC) {
    for (int idx = tid; idx < PW_KC * PW_TP; idx += 256) {
      int kk = idx / PW_TP, p = idx - kk * PW_TP;
      int c = k0 + kk;
      float v = in[((size_t)(b * K + c)) * PLANE_A + pp0 + p];
      xs[kk][p] = fmaxf(fmaf(v, scl[c], shl[c]), 0.f);
    }
    for (int idx = tid; idx < PW_KC * PW_TO; idx += 256) {
      int kk = idx / PW_TO, o = idx - kk * PW_TO;
      ws[kk][o] = (o < O) ? w[o * K + k0 + kk] : 0.f;
    }
    __syncthreads();
    #pragma unroll 4
    for (int kk = 0; kk < PW_KC; kk++) {
      float x0 = xs[kk][tx * 4 + 0], x1 = xs[kk][tx * 4 + 1];
      float x2 = xs[kk][tx * 4 + 2], x3 = xs[kk][tx * 4 + 3];
      const float* wr = &ws[kk][ty * 12];
      #pragma unroll
      for (int o = 0; o < 12; o++) {
        float wv = wr[o];
        acc[0][o] = fmaf(x0, wv, acc[0][o]);
        acc[1][o] = fmaf(x1, wv, acc[1][o]);
        acc[2][o] = fmaf(x2, wv, acc[2][o]);
        acc[3][o] = fmaf(x3, wv, acc[3][o]);
      }
    }
    __syncthreads();
  }
  #pragma unroll
  for (int o = 0; o < 12; o++) {
    int oo = ty * 12 + o;
    if (oo < O) {
      float* op = out + ((size_t)(b * O + oo)) * PLANE_A + pp0 + tx * 4;
      op[0] = acc[0][o]; op[1] = acc[1][o]; op[2] = acc[2][o]; op[3] = acc[3][o];
    }
  }
}

// ===== final: 1x1 conv 180->9 + softmax + disparity expectation =====
__global__ __launch_bounds__(256) void k_final(const float* __restrict__ in,
    const float* __restrict__ sc, const float* __restrict__ sh,
    const float* __restrict__ w, float* __restrict__ out) {
  __shared__ float wl[9 * 180];
  __shared__ float scl[180], shl[180];
  int tid = threadIdx.x;
  for (int k = tid; k < 1620; k += 256) wl[k] = w[k];
  for (int c = tid; c < 180; c += 256) { scl[c] = sc[c]; shl[c] = sh[c]; }
  __syncthreads();
  int t = blockIdx.x * 256 + tid;
  int b = t / PLANE_A, p = t - b * PLANE_A;
  float acc[9];
  #pragma unroll
  for (int o = 0; o < 9; o++) acc[o] = 0.f;
  for (int c = 0; c < 180; c++) {
    float v = fmaxf(fmaf(in[((size_t)(b * 180 + c)) * PLANE_A + p], scl[c], shl[c]), 0.f);
    #pragma unroll
    for (int o = 0; o < 9; o++) acc[o] = fmaf(wl[o * 180 + c], v, acc[o]);
  }
  float m = acc[0];
  #pragma unroll
  for (int o = 1; o < 9; o++) m = fmaxf(m, acc[o]);
  float se = 0.f, num = 0.f;
  #pragma unroll
  for (int o = 0; o < 9; o++) {
    float e = expf(acc[o] - m);
    se += e;
    num += (float)(o - 4) * e;
  }
  out[t] = num / se;
}

extern "C" void kernel_launch(void* const* d_in, const int* in_sizes, int n_in,
                              void* d_out, int out_size, void* d_ws, size_t ws_size,
                              hipStream_t stream) {
  const float* x    = (const float*)d_in[0];
  const float* fw0  = (const float*)d_in[1];
  const float* fg0  = (const float*)d_in[2];
  const float* fb0  = (const float*)d_in[3];
  const float* fw   = (const float*)d_in[4];
  const float* fg   = (const float*)d_in[5];
  const float* fb   = (const float*)d_in[6];
  const float* bcw  = (const float*)d_in[7];
  const float* a0dw = (const float*)d_in[8];
  const float* a0dg = (const float*)d_in[9];
  const float* a0db = (const float*)d_in[10];
  const float* a0pw = (const float*)d_in[11];
  const float* a0pg = (const float*)d_in[12];
  const float* a0pb = (const float*)d_in[13];
  const float* amdw = (const float*)d_in[14];
  const float* amdg = (const float*)d_in[15];
  const float* amdb = (const float*)d_in[16];
  const float* ampw = (const float*)d_in[17];
  const float* ampg = (const float*)d_in[18];
  const float* ampb = (const float*)d_in[19];
  const float* ldw  = (const float*)d_in[20];
  const float* ldg  = (const float*)d_in[21];
  const float* ldb  = (const float*)d_in[22];
  const float* lpw  = (const float*)d_in[23];
  float* outp = (float*)d_out;

  float* FA    = (float*)d_ws;
  float* FB    = FA + (size_t)BB * 7 * PLANE_F;
  float* CV    = FB + (size_t)BB * 7 * PLANE_F;
  float* GA    = CV + (size_t)BB * 144 * PLANE_A;
  float* GB    = GA + (size_t)BB * 180 * PLANE_A;
  float* PART  = GB + (size_t)BB * 180 * PLANE_A;
  float* SC    = PART + 180 * 64 * 2;
  float* SH    = SC + 180;

  const int nblk_f = BB * PLANE_F / 256;             // 5832

  // feature extraction in SAI-view layout (MacPI rearrange folded away)
  k_featconv0<<<nblk_f, 256, 0, stream>>>(x, fw0, FA);
  k_stats_partial<<<7 * 64, 256, 0, stream>>>(FA, PART, 7, PLANE_F, 64);
  k_stats_final<<<1, 64, 0, stream>>>(PART, fg0, fb0, SC, SH, 7, 64, 1.0f / (float)(BB * PLANE_F));

  float* cur = FA; float* nxt = FB;
  for (int i = 0; i < 6; i++) {
    k_featconv<<<nblk_f, 256, 0, stream>>>(cur, fw + i * 441, SC, SH, nxt);
    k_stats_partial<<<7 * 64, 256, 0, stream>>>(nxt, PART, 7, PLANE_F, 64);
    k_stats_final<<<1, 64, 0, stream>>>(PART, fg + i * 7, fb + i * 7, SC, SH, 7, 64,
                                        1.0f / (float)(BB * PLANE_F));
    float* tmp = cur; cur = nxt; nxt = tmp;
  }

  // BuildCost (disp_shift folded, SAI sampling)
  k_buildcost<<<dim3(36, 9, 2), 256, 0, stream>>>(cur, SC, SH, bcw, CV);

  // aggregation
  k_dwconv<false><<<BB * 144 * PLANE_A / 256, 256, 0, stream>>>(CV, a0dw, nullptr, nullptr, GA, 144);
  k_stats_small<<<144, 256, 0, stream>>>(GA, a0dg, a0db, SC, SH, 144);
  k_pwconv<144><<<288, 256, 0, stream>>>(GA, SC, SH, a0pw, GB, 180);
  k_stats_small<<<180, 256, 0, stream>>>(GB, a0pg, a0pb, SC, SH, 180);

  for (int m = 0; m < 4; m++) {
    k_dwconv<true><<<BB * 180 * PLANE_A / 256, 256, 0, stream>>>(GB, amdw + m * 1620, SC, SH, GA, 180);
    k_stats_small<<<180, 256, 0, stream>>>(GA, amdg + m * 180, amdb + m * 180, SC, SH, 180);
    k_pwconv<180><<<288, 256, 0, stream>>>(GA, SC, SH, ampw + m * 32400, GB, 180);
    k_stats_small<<<180, 256, 0, stream>>>(GB, ampg + m * 180, ampb + m * 180, SC, SH, 180);
  }

  k_dwconv<true><<<BB * 180 * PLANE_A / 256, 256, 0, stream>>>(GB, ldw, SC, SH, GA, 180);
  k_stats_small<<<180, 256, 0, stream>>>(GA, ldg, ldb, SC, SH, 180);

  k_final<<<72, 256, 0, stream>>>(GA, SC, SH, lpw, outp);
}

// Round 4
// 1409.757 us; speedup vs baseline: 3.8759x; 1.3113x over previous
//
#include <hip/hip_runtime.h>

#define ANG 9
#define HH 96
#define BB 2
#define PLANE_F (81*HH*HH)  // 746496 per channel (81 views x 96x96)
#define PLANE_A (HH*HH)     // 9216
#define NBLK_FEAT 1458      // BB*81*9 blocks (each: 256 threads, 4-row strips)

// ===== generic BN-final: reduce per-block partials -> scale/shift =====
// psum/psq layout: [c*NB + k], grid = C blocks
__global__ __launch_bounds__(256) void k_bnfinal(const float* __restrict__ psum,
    const float* __restrict__ psq, const float* __restrict__ g, const float* __restrict__ bbias,
    float* __restrict__ sc, float* __restrict__ sh, int NB, float invN) {
  int c = blockIdx.x, tid = threadIdx.x;
  float s = 0.f, q = 0.f;
  for (int k = tid; k < NB; k += 256) { s += psum[c * NB + k]; q += psq[c * NB + k]; }
  __shared__ float ss[256], qq[256];
  ss[tid] = s; qq[tid] = q;
  __syncthreads();
  for (int st = 128; st > 0; st >>= 1) {
    if (tid < st) { ss[tid] += ss[tid + st]; qq[tid] += qq[tid + st]; }
    __syncthreads();
  }
  if (tid == 0) {
    float mean = ss[0] * invN;
    float var = fmaxf(qq[0] * invN - mean * mean, 0.f);
    float scale = g[c] / sqrtf(var + 1e-5f);
    sc[c] = scale; sh[c] = bbias[c] - mean * scale;
  }
}

// ===== feature conv0: 1->7 from raw x (SAI views), 4-row strip/thread, fused stats =====
__global__ __launch_bounds__(256) void k_featconv0(const float* __restrict__ x,
    const float* __restrict__ w, float* __restrict__ out,
    float* __restrict__ psum, float* __restrict__ psq) {
  int blk = blockIdx.x, tid = threadIdx.x;
  int view = blk / 9, q = blk % 9;
  int b = view / 81, uv = view % 81;
  int u = uv / 9, v = uv % 9;
  int widx = q * 256 + tid;                         // 0..2303
  int j = widx % HH, i0 = (widx / HH) * 4;
  const float* bx = x + (size_t)b * PLANE_F + (u * HH) * 864 + v * HH;
  float acc[4][7];
  #pragma unroll
  for (int px = 0; px < 4; px++)
    #pragma unroll
    for (int o = 0; o < 7; o++) acc[px][o] = 0.f;
  float win[6][3];
  #pragma unroll
  for (int r6 = 0; r6 < 6; r6++) {
    int ii = i0 + r6 - 1;
    bool okr = (unsigned)ii < (unsigned)HH;
    #pragma unroll
    for (int dx = 0; dx < 3; dx++) {
      int jj = j + dx - 1;
      bool ok = okr && ((unsigned)jj < (unsigned)HH);
      win[r6][dx] = ok ? bx[ii * 864 + jj] : 0.f;
    }
  }
  #pragma unroll
  for (int o = 0; o < 7; o++) {
    const float* wc = w + o * 9;
    #pragma unroll
    for (int ky = 0; ky < 3; ky++)
      #pragma unroll
      for (int kx = 0; kx < 3; kx++) {
        float wv = wc[ky * 3 + kx];
        #pragma unroll
        for (int px = 0; px < 4; px++)
          acc[px][o] = fmaf(win[px + ky][kx], wv, acc[px][o]);
      }
  }
  #pragma unroll
  for (int o = 0; o < 7; o++) {
    float* op = out + ((size_t)(b * 7 + o)) * PLANE_F + uv * PLANE_A + i0 * HH + j;
    #pragma unroll
    for (int px = 0; px < 4; px++) op[px * HH] = acc[px][o];
  }
  // fused raw-output stats
  float sv[7], qv[7];
  #pragma unroll
  for (int o = 0; o < 7; o++) {
    sv[o] = acc[0][o] + acc[1][o] + acc[2][o] + acc[3][o];
    qv[o] = acc[0][o]*acc[0][o] + acc[1][o]*acc[1][o] + acc[2][o]*acc[2][o] + acc[3][o]*acc[3][o];
  }
  #pragma unroll
  for (int off = 32; off > 0; off >>= 1)
    #pragma unroll
    for (int o = 0; o < 7; o++) { sv[o] += __shfl_down(sv[o], off); qv[o] += __shfl_down(qv[o], off); }
  __shared__ float red[4][14];
  int wave = tid >> 6, lane = tid & 63;
  if (lane == 0) {
    #pragma unroll
    for (int o = 0; o < 7; o++) { red[wave][o] = sv[o]; red[wave][7 + o] = qv[o]; }
  }
  __syncthreads();
  if (tid < 14) {
    float t4 = red[0][tid] + red[1][tid] + red[2][tid] + red[3][tid];
    if (tid < 7) psum[tid * NBLK_FEAT + blk] = t4;
    else         psq[(tid - 7) * NBLK_FEAT + blk] = t4;
  }
}

// ===== feature conv: 7->7, fused input BN+ReLU, 4-row strip/thread, fused stats =====
__global__ __launch_bounds__(256) void k_featconv4(const float* __restrict__ in,
    const float* __restrict__ w, const float* __restrict__ sc, const float* __restrict__ sh,
    float* __restrict__ out, float* __restrict__ psum, float* __restrict__ psq) {
  int blk = blockIdx.x, tid = threadIdx.x;
  int view = blk / 9, q = blk % 9;
  int b = view / 81, uv = view % 81;
  int widx = q * 256 + tid;
  int j = widx % HH, i0 = (widx / HH) * 4;
  float acc[4][7];
  #pragma unroll
  for (int px = 0; px < 4; px++)
    #pragma unroll
    for (int o = 0; o < 7; o++) acc[px][o] = 0.f;
  #pragma unroll 1
  for (int c = 0; c < 7; c++) {
    const float* ip = in + ((size_t)(b * 7 + c)) * PLANE_F + uv * PLANE_A;
    float s = sc[c], h2 = sh[c];
    float win[6][3];
    #pragma unroll
    for (int r6 = 0; r6 < 6; r6++) {
      int ii = i0 + r6 - 1;
      bool okr = (unsigned)ii < (unsigned)HH;
      #pragma unroll
      for (int dx = 0; dx < 3; dx++) {
        int jj = j + dx - 1;
        bool ok = okr && ((unsigned)jj < (unsigned)HH);
        float vv = ok ? ip[ii * HH + jj] : 0.f;
        win[r6][dx] = ok ? fmaxf(fmaf(vv, s, h2), 0.f) : 0.f;
      }
    }
    #pragma unroll
    for (int o = 0; o < 7; o++) {
      const float* wc = w + (o * 7 + c) * 9;
      #pragma unroll
      for (int ky = 0; ky < 3; ky++)
        #pragma unroll
        for (int kx = 0; kx < 3; kx++) {
          float wv = wc[ky * 3 + kx];
          #pragma unroll
          for (int px = 0; px < 4; px++)
            acc[px][o] = fmaf(win[px + ky][kx], wv, acc[px][o]);
        }
    }
  }
  #pragma unroll
  for (int o = 0; o < 7; o++) {
    float* op = out + ((size_t)(b * 7 + o)) * PLANE_F + uv * PLANE_A + i0 * HH + j;
    #pragma unroll
    for (int px = 0; px < 4; px++) op[px * HH] = acc[px][o];
  }
  float sv[7], qv[7];
  #pragma unroll
  for (int o = 0; o < 7; o++) {
    sv[o] = acc[0][o] + acc[1][o] + acc[2][o] + acc[3][o];
    qv[o] = acc[0][o]*acc[0][o] + acc[1][o]*acc[1][o] + acc[2][o]*acc[2][o] + acc[3][o]*acc[3][o];
  }
  #pragma unroll
  for (int off = 32; off > 0; off >>= 1)
    #pragma unroll
    for (int o = 0; o < 7; o++) { sv[o] += __shfl_down(sv[o], off); qv[o] += __shfl_down(qv[o], off); }
  __shared__ float red[4][14];
  int wave = tid >> 6, lane = tid & 63;
  if (lane == 0) {
    #pragma unroll
    for (int o = 0; o < 7; o++) { red[wave][o] = sv[o]; red[wave][7 + o] = qv[o]; }
  }
  __syncthreads();
  if (tid < 14) {
    float t4 = red[0][tid] + red[1][tid] + red[2][tid] + red[3][tid];
    if (tid < 7) psum[tid * NBLK_FEAT + blk] = t4;
    else         psq[(tid - 7) * NBLK_FEAT + blk] = t4;
  }
}

// ===== BuildCost, o-split for occupancy: grid (36, 18, 2), 8 outputs/block =====
__global__ __launch_bounds__(256, 8) void k_buildcost(const float* __restrict__ F,
    const float* __restrict__ sc, const float* __restrict__ sh,
    const float* __restrict__ w, float* __restrict__ cv) {
  __shared__ float wl[4536];                        // [c*81+u*9+v][o8]
  __shared__ float scl[7], shl[7];
  int gg = blockIdx.y, b = blockIdx.z, tid = threadIdx.x;
  int g = gg >> 1, half = gg & 1;
  for (int k = tid; k < 4536; k += 256) {
    int o = k & 7; int r = k >> 3;                  // r = c*81 + u*9 + v
    wl[k] = w[(g * 16 + half * 8 + o) * 567 + r];
  }
  if (tid < 7) { scl[tid] = sc[tid]; shl[tid] = sh[tid]; }
  __syncthreads();
  int d = g - 4;
  bool flip = d > 0;
  int p = blockIdx.x * 256 + tid;
  int i = p / HH, j = p % HH;
  float acc[8];
  #pragma unroll
  for (int o = 0; o < 8; o++) acc[o] = 0.f;
  #pragma unroll 1
  for (int c = 0; c < 7; c++) {
    const float* Fc = F + ((size_t)(b * 7 + c)) * PLANE_F;
    float s = scl[c], h2 = shl[c];
    #pragma unroll 1
    for (int u = 0; u < 9; u++) {
      int ii = i + d * (4 - u);
      bool okI = (unsigned)ii < (unsigned)HH;
      int uw = flip ? 8 - u : u;
      const float* Frow = Fc + (u * 9) * PLANE_A + ii * HH;
      const float* wu = &wl[(c * 81 + uw * 9) * 8];
      float vals[9];
      #pragma unroll
      for (int v = 0; v < 9; v++) {
        int jj = j + d * (4 - v);
        bool ok = okI && ((unsigned)jj < (unsigned)HH);
        vals[v] = ok ? fmaxf(fmaf(Frow[v * PLANE_A + jj], s, h2), 0.f) : 0.f;
      }
      #pragma unroll
      for (int v = 0; v < 9; v++) {
        int vw = flip ? 8 - v : v;
        const float* wv = wu + vw * 8;
        float a = vals[v];
        #pragma unroll
        for (int o = 0; o < 8; o++) acc[o] = fmaf(wv[o], a, acc[o]);
      }
    }
  }
  size_t cvb = ((size_t)(b * 144 + g * 16 + half * 8)) * PLANE_A + p;
  #pragma unroll
  for (int o = 0; o < 8; o++) cv[cvb + o * PLANE_A] = acc[o];
}

// ===== depthwise 3x3 pad=1, fused input BN+ReLU + fused output stats =====
// psum layout: [c*72 + b*36 + chunk]
template<bool AFF>
__global__ __launch_bounds__(256) void k_dwconv(const float* __restrict__ in,
    const float* __restrict__ w, const float* __restrict__ isc, const float* __restrict__ ish,
    float* __restrict__ out, float* __restrict__ psum, float* __restrict__ psq, int C) {
  int blk = blockIdx.x, tid = threadIdx.x;
  int t = blk * 256 + tid;
  int j = t % HH; int r = t / HH; int i = r % HH; r /= HH; int c = r % C; int b = r / C;
  float s  = AFF ? isc[c] : 1.f;
  float h2 = AFF ? ish[c] : 0.f;
  const float* ip = in + ((size_t)(b * C + c)) * PLANE_A;
  float acc = 0.f;
  #pragma unroll
  for (int ky = 0; ky < 3; ky++) {
    int ii = i + ky - 1;
    if ((unsigned)ii >= (unsigned)HH) continue;
    #pragma unroll
    for (int kx = 0; kx < 3; kx++) {
      int jj = j + kx - 1;
      if ((unsigned)jj >= (unsigned)HH) continue;
      float v = ip[ii * HH + jj];
      if (AFF) v = fmaxf(fmaf(v, s, h2), 0.f);
      acc = fmaf(w[c * 9 + ky * 3 + kx], v, acc);
    }
  }
  out[t] = acc;
  float sv = acc, qv = acc * acc;
  #pragma unroll
  for (int off = 32; off > 0; off >>= 1) { sv += __shfl_down(sv, off); qv += __shfl_down(qv, off); }
  __shared__ float red[4][2];
  int wave = tid >> 6, lane = tid & 63;
  if (lane == 0) { red[wave][0] = sv; red[wave][1] = qv; }
  __syncthreads();
  if (tid == 0) {
    float S = red[0][0] + red[1][0] + red[2][0] + red[3][0];
    float Q = red[0][1] + red[1][1] + red[2][1] + red[3][1];
    int chunk = blk % 36; int rr = blk / 36; int c2 = rr % C; int b2 = rr / C;
    psum[c2 * 72 + b2 * 36 + chunk] = S;
    psq [c2 * 72 + b2 * 36 + chunk] = Q;
  }
}

// ===== pointwise conv (GEMM), fused input BN+ReLU + fused output stats =====
#define PW_TP 64
#define PW_TO 192
#define PW_KC 36
template<int K>
__global__ __launch_bounds__(256) void k_pwconv(const float* __restrict__ in,
    const float* __restrict__ sc, const float* __restrict__ sh,
    const float* __restrict__ w, float* __restrict__ out,
    float* __restrict__ psum, float* __restrict__ psq, int O) {
  __shared__ float xs[PW_KC][PW_TP];
  __shared__ float ws[PW_KC][PW_TO];
  __shared__ float scl[K], shl[K];
  int tid = threadIdx.x;
  for (int c = tid; c < K; c += 256) { scl[c] = sc[c]; shl[c] = sh[c]; }
  __syncthreads();
  int tile = blockIdx.x;
  int p0 = tile * PW_TP;
  int b = p0 / PLANE_A;
  int pp0 = p0 - b * PLANE_A;
  int tx = tid % 16, ty = tid / 16;
  float acc[4][12];
  #pragma unroll
  for (int qd = 0; qd < 4; qd++)
    #pragma unroll
    for (int o = 0; o < 12; o++) acc[qd][o] = 0.f;
  for (int k0 = 0; k0 < K; k0 += PW_KC) {
    for (int idx = tid; idx < PW_KC * PW_TP; idx += 256) {
      int kk = idx / PW_TP, p = idx - kk * PW_TP;
      int c = k0 + kk;
      float v = in[((size_t)(b * K + c)) * PLANE_A + pp0 + p];
      xs[kk][p] = fmaxf(fmaf(v, scl[c], shl[c]), 0.f);
    }
    for (int idx = tid; idx < PW_KC * PW_TO; idx += 256) {
      int kk = idx / PW_TO, o = idx - kk * PW_TO;
      ws[kk][o] = (o < O) ? w[o * K + k0 + kk] : 0.f;
    }
    __syncthreads();
    #pragma unroll 4
    for (int kk = 0; kk < PW_KC; kk++) {
      float x0 = xs[kk][tx * 4 + 0], x1 = xs[kk][tx * 4 + 1];
      float x2 = xs[kk][tx * 4 + 2], x3 = xs[kk][tx * 4 + 3];
      const float* wr = &ws[kk][ty * 12];
      #pragma unroll
      for (int o = 0; o < 12; o++) {
        float wv = wr[o];
        acc[0][o] = fmaf(x0, wv, acc[0][o]);
        acc[1][o] = fmaf(x1, wv, acc[1][o]);
        acc[2][o] = fmaf(x2, wv, acc[2][o]);
        acc[3][o] = fmaf(x3, wv, acc[3][o]);
      }
    }
    __syncthreads();
  }
  #pragma unroll
  for (int o = 0; o < 12; o++) {
    int oo = ty * 12 + o;
    if (oo < O) {
      float* op = out + ((size_t)(b * O + oo)) * PLANE_A + pp0 + tx * 4;
      op[0] = acc[0][o]; op[1] = acc[1][o]; op[2] = acc[2][o]; op[3] = acc[3][o];
    }
  }
  // fused stats: reduce over tx (16 lanes, same wave) for each of ty's 12 outputs
  #pragma unroll
  for (int o = 0; o < 12; o++) {
    float s = acc[0][o] + acc[1][o] + acc[2][o] + acc[3][o];
    float q = acc[0][o]*acc[0][o] + acc[1][o]*acc[1][o] + acc[2][o]*acc[2][o] + acc[3][o]*acc[3][o];
    #pragma unroll
    for (int off = 1; off < 16; off <<= 1) { s += __shfl_xor(s, off); q += __shfl_xor(q, off); }
    int oo = ty * 12 + o;
    if (tx == 0 && oo < O) { psum[oo * 288 + tile] = s; psq[oo * 288 + tile] = q; }
  }
}

// ===== final: 1x1 conv 180->9 + softmax + disparity expectation =====
__global__ __launch_bounds__(256) void k_final(const float* __restrict__ in,
    const float* __restrict__ sc, const float* __restrict__ sh,
    const float* __restrict__ w, float* __restrict__ out) {
  __shared__ float wl[9 * 180];
  __shared__ float scl[180], shl[180];
  int tid = threadIdx.x;
  for (int k = tid; k < 1620; k += 256) wl[k] = w[k];
  for (int c = tid; c < 180; c += 256) { scl[c] = sc[c]; shl[c] = sh[c]; }
  __syncthreads();
  int t = blockIdx.x * 256 + tid;
  int b = t / PLANE_A, p = t - b * PLANE_A;
  float acc[9];
  #pragma unroll
  for (int o = 0; o < 9; o++) acc[o] = 0.f;
  for (int c = 0; c < 180; c++) {
    float v = fmaxf(fmaf(in[((size_t)(b * 180 + c)) * PLANE_A + p], scl[c], shl[c]), 0.f);
    #pragma unroll
    for (int o = 0; o < 9; o++) acc[o] = fmaf(wl[o * 180 + c], v, acc[o]);
  }
  float m = acc[0];
  #pragma unroll
  for (int o = 1; o < 9; o++) m = fmaxf(m, acc[o]);
  float se = 0.f, num = 0.f;
  #pragma unroll
  for (int o = 0; o < 9; o++) {
    float e = expf(acc[o] - m);
    se += e;
    num += (float)(o - 4) * e;
  }
  out[t] = num / se;
}

extern "C" void kernel_launch(void* const* d_in, const int* in_sizes, int n_in,
                              void* d_out, int out_size, void* d_ws, size_t ws_size,
                              hipStream_t stream) {
  const float* x    = (const float*)d_in[0];
  const float* fw0  = (const float*)d_in[1];
  const float* fg0  = (const float*)d_in[2];
  const float* fb0  = (const float*)d_in[3];
  const float* fw   = (const float*)d_in[4];
  const float* fg   = (const float*)d_in[5];
  const float* fb   = (const float*)d_in[6];
  const float* bcw  = (const float*)d_in[7];
  const float* a0dw = (const float*)d_in[8];
  const float* a0dg = (const float*)d_in[9];
  const float* a0db = (const float*)d_in[10];
  const float* a0pw = (const float*)d_in[11];
  const float* a0pg = (const float*)d_in[12];
  const float* a0pb = (const float*)d_in[13];
  const float* amdw = (const float*)d_in[14];
  const float* amdg = (const float*)d_in[15];
  const float* amdb = (const float*)d_in[16];
  const float* ampw = (const float*)d_in[17];
  const float* ampg = (const float*)d_in[18];
  const float* ampb = (const float*)d_in[19];
  const float* ldw  = (const float*)d_in[20];
  const float* ldg  = (const float*)d_in[21];
  const float* ldb  = (const float*)d_in[22];
  const float* lpw  = (const float*)d_in[23];
  float* outp = (float*)d_out;

  float* FA    = (float*)d_ws;
  float* FB    = FA + (size_t)BB * 7 * PLANE_F;
  float* CV    = FB + (size_t)BB * 7 * PLANE_F;
  float* GA    = CV + (size_t)BB * 144 * PLANE_A;
  float* GB    = GA + (size_t)BB * 180 * PLANE_A;
  float* PSUM  = GB + (size_t)BB * 180 * PLANE_A;
  float* PSQ   = PSUM + 180 * 288;
  float* SC    = PSQ + 180 * 288;
  float* SH    = SC + 180;

  const float invNbig = 1.0f / (float)(BB * PLANE_F);
  const float invNsmall = 1.0f / (float)(BB * PLANE_A);

  // feature extraction (SAI layout), stats fused into conv blocks
  k_featconv0<<<NBLK_FEAT, 256, 0, stream>>>(x, fw0, FA, PSUM, PSQ);
  k_bnfinal<<<7, 256, 0, stream>>>(PSUM, PSQ, fg0, fb0, SC, SH, NBLK_FEAT, invNbig);

  float* cur = FA; float* nxt = FB;
  for (int i = 0; i < 6; i++) {
    k_featconv4<<<NBLK_FEAT, 256, 0, stream>>>(cur, fw + i * 441, SC, SH, nxt, PSUM, PSQ);
    k_bnfinal<<<7, 256, 0, stream>>>(PSUM, PSQ, fg + i * 7, fb + i * 7, SC, SH, NBLK_FEAT, invNbig);
    float* tmp = cur; cur = nxt; nxt = tmp;
  }

  // BuildCost (o-split: 1296 blocks for occupancy)
  k_buildcost<<<dim3(36, 18, 2), 256, 0, stream>>>(cur, SC, SH, bcw, CV);

  // aggregation (stats fused everywhere)
  k_dwconv<false><<<BB * 144 * 36, 256, 0, stream>>>(CV, a0dw, nullptr, nullptr, GA, PSUM, PSQ, 144);
  k_bnfinal<<<144, 256, 0, stream>>>(PSUM, PSQ, a0dg, a0db, SC, SH, 72, invNsmall);
  k_pwconv<144><<<288, 256, 0, stream>>>(GA, SC, SH, a0pw, GB, PSUM, PSQ, 180);
  k_bnfinal<<<180, 256, 0, stream>>>(PSUM, PSQ, a0pg, a0pb, SC, SH, 288, invNsmall);

  for (int m = 0; m < 4; m++) {
    k_dwconv<true><<<BB * 180 * 36, 256, 0, stream>>>(GB, amdw + m * 1620, SC, SH, GA, PSUM, PSQ, 180);
    k_bnfinal<<<180, 256, 0, stream>>>(PSUM, PSQ, amdg + m * 180, amdb + m * 180, SC, SH, 72, invNsmall);
    k_pwconv<180><<<288, 256, 0, stream>>>(GA, SC, SH, ampw + m * 32400, GB, PSUM, PSQ, 180);
    k_bnfinal<<<180, 256, 0, stream>>>(PSUM, PSQ, ampg + m * 180, ampb + m * 180, SC, SH, 288, invNsmall);
  }

  k_dwconv<true><<<BB * 180 * 36, 256, 0, stream>>>(GB, ldw, SC, SH, GA, PSUM, PSQ, 180);
  k_bnfinal<<<180, 256, 0, stream>>>(PSUM, PSQ, ldg, ldb, SC, SH, 72, invNsmall);

  k_final<<<72, 256, 0, stream>>>(GA, SC, SH, lpw, outp);
}

// Round 5
// 1382.886 us; speedup vs baseline: 3.9512x; 1.0194x over previous
//
#include <hip/hip_runtime.h>

#define ANG 9
#define HH 96
#define BB 2
#define PLANE_F (81*HH*HH)  // 746496 per channel (81 views x 96x96)
#define PLANE_A (HH*HH)     // 9216
#define NBLK_FEAT 1458      // BB*81*9 blocks (each: 256 threads, 4-row strips)

// ===== generic BN-final: reduce per-block partials -> scale/shift =====
__global__ __launch_bounds__(256) void k_bnfinal(const float* __restrict__ psum,
    const float* __restrict__ psq, const float* __restrict__ g, const float* __restrict__ bbias,
    float* __restrict__ sc, float* __restrict__ sh, int NB, float invN) {
  int c = blockIdx.x, tid = threadIdx.x;
  float s = 0.f, q = 0.f;
  for (int k = tid; k < NB; k += 256) { s += psum[c * NB + k]; q += psq[c * NB + k]; }
  __shared__ float ss[256], qq[256];
  ss[tid] = s; qq[tid] = q;
  __syncthreads();
  for (int st = 128; st > 0; st >>= 1) {
    if (tid < st) { ss[tid] += ss[tid + st]; qq[tid] += qq[tid + st]; }
    __syncthreads();
  }
  if (tid == 0) {
    float mean = ss[0] * invN;
    float var = fmaxf(qq[0] * invN - mean * mean, 0.f);
    float scale = g[c] / sqrtf(var + 1e-5f);
    sc[c] = scale; sh[c] = bbias[c] - mean * scale;
  }
}

// ===== weight pre-shuffle for BuildCost: WT[((g*7+c)*81 + u*9+v)*16 + o] =====
__global__ __launch_bounds__(256) void k_wprep(const float* __restrict__ w, float* __restrict__ wt) {
  int k = blockIdx.x * 256 + threadIdx.x;
  if (k >= 144 * 567) return;
  int o = k & 15; int rest = k >> 4;
  int r81 = rest % 81; int gc = rest / 81;
  int c = gc % 7, g = gc / 7;
  wt[k] = w[((g * 16 + o) * 7 + c) * 81 + r81];
}

// ===== feature conv0: 1->7 from raw x (SAI views), 4-row strip/thread, fused stats =====
__global__ __launch_bounds__(256) void k_featconv0(const float* __restrict__ x,
    const float* __restrict__ w, float* __restrict__ out,
    float* __restrict__ psum, float* __restrict__ psq) {
  int blk = blockIdx.x, tid = threadIdx.x;
  int view = blk / 9, q = blk % 9;
  int b = view / 81, uv = view % 81;
  int u = uv / 9, v = uv % 9;
  int widx = q * 256 + tid;
  int j = widx % HH, i0 = (widx / HH) * 4;
  const float* bx = x + (size_t)b * PLANE_F + (u * HH) * 864 + v * HH;
  float acc[4][7];
  #pragma unroll
  for (int px = 0; px < 4; px++)
    #pragma unroll
    for (int o = 0; o < 7; o++) acc[px][o] = 0.f;
  float win[6][3];
  #pragma unroll
  for (int r6 = 0; r6 < 6; r6++) {
    int ii = i0 + r6 - 1;
    bool okr = (unsigned)ii < (unsigned)HH;
    #pragma unroll
    for (int dx = 0; dx < 3; dx++) {
      int jj = j + dx - 1;
      bool ok = okr && ((unsigned)jj < (unsigned)HH);
      win[r6][dx] = ok ? bx[ii * 864 + jj] : 0.f;
    }
  }
  #pragma unroll
  for (int o = 0; o < 7; o++) {
    const float* wc = w + o * 9;
    #pragma unroll
    for (int ky = 0; ky < 3; ky++)
      #pragma unroll
      for (int kx = 0; kx < 3; kx++) {
        float wv = wc[ky * 3 + kx];
        #pragma unroll
        for (int px = 0; px < 4; px++)
          acc[px][o] = fmaf(win[px + ky][kx], wv, acc[px][o]);
      }
  }
  #pragma unroll
  for (int o = 0; o < 7; o++) {
    float* op = out + ((size_t)(b * 7 + o)) * PLANE_F + uv * PLANE_A + i0 * HH + j;
    #pragma unroll
    for (int px = 0; px < 4; px++) op[px * HH] = acc[px][o];
  }
  float sv[7], qv[7];
  #pragma unroll
  for (int o = 0; o < 7; o++) {
    sv[o] = acc[0][o] + acc[1][o] + acc[2][o] + acc[3][o];
    qv[o] = acc[0][o]*acc[0][o] + acc[1][o]*acc[1][o] + acc[2][o]*acc[2][o] + acc[3][o]*acc[3][o];
  }
  #pragma unroll
  for (int off = 32; off > 0; off >>= 1)
    #pragma unroll
    for (int o = 0; o < 7; o++) { sv[o] += __shfl_down(sv[o], off); qv[o] += __shfl_down(qv[o], off); }
  __shared__ float red[4][14];
  int wave = tid >> 6, lane = tid & 63;
  if (lane == 0) {
    #pragma unroll
    for (int o = 0; o < 7; o++) { red[wave][o] = sv[o]; red[wave][7 + o] = qv[o]; }
  }
  __syncthreads();
  if (tid < 14) {
    float t4 = red[0][tid] + red[1][tid] + red[2][tid] + red[3][tid];
    if (tid < 7) psum[tid * NBLK_FEAT + blk] = t4;
    else         psq[(tid - 7) * NBLK_FEAT + blk] = t4;
  }
}

// ===== feature conv: 7->7, fused input BN+ReLU, 4-row strip/thread, fused stats =====
__global__ __launch_bounds__(256) void k_featconv4(const float* __restrict__ in,
    const float* __restrict__ w, const float* __restrict__ sc, const float* __restrict__ sh,
    float* __restrict__ out, float* __restrict__ psum, float* __restrict__ psq) {
  int blk = blockIdx.x, tid = threadIdx.x;
  int view = blk / 9, q = blk % 9;
  int b = view / 81, uv = view % 81;
  int widx = q * 256 + tid;
  int j = widx % HH, i0 = (widx / HH) * 4;
  float acc[4][7];
  #pragma unroll
  for (int px = 0; px < 4; px++)
    #pragma unroll
    for (int o = 0; o < 7; o++) acc[px][o] = 0.f;
  #pragma unroll 1
  for (int c = 0; c < 7; c++) {
    const float* ip = in + ((size_t)(b * 7 + c)) * PLANE_F + uv * PLANE_A;
    float s = sc[c], h2 = sh[c];
    float win[6][3];
    #pragma unroll
    for (int r6 = 0; r6 < 6; r6++) {
      int ii = i0 + r6 - 1;
      bool okr = (unsigned)ii < (unsigned)HH;
      #pragma unroll
      for (int dx = 0; dx < 3; dx++) {
        int jj = j + dx - 1;
        bool ok = okr && ((unsigned)jj < (unsigned)HH);
        float vv = ok ? ip[ii * HH + jj] : 0.f;
        win[r6][dx] = ok ? fmaxf(fmaf(vv, s, h2), 0.f) : 0.f;
      }
    }
    #pragma unroll
    for (int o = 0; o < 7; o++) {
      const float* wc = w + (o * 7 + c) * 9;
      #pragma unroll
      for (int ky = 0; ky < 3; ky++)
        #pragma unroll
        for (int kx = 0; kx < 3; kx++) {
          float wv = wc[ky * 3 + kx];
          #pragma unroll
          for (int px = 0; px < 4; px++)
            acc[px][o] = fmaf(win[px + ky][kx], wv, acc[px][o]);
        }
    }
  }
  #pragma unroll
  for (int o = 0; o < 7; o++) {
    float* op = out + ((size_t)(b * 7 + o)) * PLANE_F + uv * PLANE_A + i0 * HH + j;
    #pragma unroll
    for (int px = 0; px < 4; px++) op[px * HH] = acc[px][o];
  }
  float sv[7], qv[7];
  #pragma unroll
  for (int o = 0; o < 7; o++) {
    sv[o] = acc[0][o] + acc[1][o] + acc[2][o] + acc[3][o];
    qv[o] = acc[0][o]*acc[0][o] + acc[1][o]*acc[1][o] + acc[2][o]*acc[2][o] + acc[3][o]*acc[3][o];
  }
  #pragma unroll
  for (int off = 32; off > 0; off >>= 1)
    #pragma unroll
    for (int o = 0; o < 7; o++) { sv[o] += __shfl_down(sv[o], off); qv[o] += __shfl_down(qv[o], off); }
  __shared__ float red[4][14];
  int wave = tid >> 6, lane = tid & 63;
  if (lane == 0) {
    #pragma unroll
    for (int o = 0; o < 7; o++) { red[wave][o] = sv[o]; red[wave][7 + o] = qv[o]; }
  }
  __syncthreads();
  if (tid < 14) {
    float t4 = red[0][tid] + red[1][tid] + red[2][tid] + red[3][tid];
    if (tid < 7) psum[tid * NBLK_FEAT + blk] = t4;
    else         psq[(tid - 7) * NBLK_FEAT + blk] = t4;
  }
}

// ===== BuildCost: scalar (SGPR) weights from pre-shuffled WT, no LDS =====
// grid (36, 9, 2), 256 thr, 16 outputs/thread.
__global__ __launch_bounds__(256) void k_buildcost(const float* __restrict__ F,
    const float* __restrict__ sc, const float* __restrict__ sh,
    const float* __restrict__ wt, float* __restrict__ cv) {
  int g = blockIdx.y, b = blockIdx.z, tid = threadIdx.x;
  int d = g - 4;
  bool flip = d > 0;
  int p = blockIdx.x * 256 + tid;
  int i = p / HH, j = p % HH;
  float acc[16];
  #pragma unroll
  for (int o = 0; o < 16; o++) acc[o] = 0.f;
  #pragma unroll 1
  for (int c = 0; c < 7; c++) {
    const float* Fc = F + ((size_t)(b * 7 + c)) * PLANE_F;
    float s = sc[c], h2 = sh[c];                    // uniform -> s_load
    const float* wc = wt + (size_t)(g * 7 + c) * 81 * 16;
    #pragma unroll 1
    for (int u = 0; u < 9; u++) {
      int ii = i + d * (4 - u);
      bool okI = (unsigned)ii < (unsigned)HH;
      int uw = flip ? 8 - u : u;
      const float* Frow = Fc + (u * 9) * PLANE_A + ii * HH;
      float vals[9];
      #pragma unroll
      for (int v = 0; v < 9; v++) {
        int jj = j + d * (4 - v);
        bool ok = okI && ((unsigned)jj < (unsigned)HH);
        vals[v] = ok ? fmaxf(fmaf(Frow[v * PLANE_A + jj], s, h2), 0.f) : 0.f;
      }
      const float* wu = wc + uw * 9 * 16;
      #pragma unroll
      for (int v = 0; v < 9; v++) {
        int vw = flip ? 8 - v : v;
        const float* wv = wu + vw * 16;             // uniform -> s_load_dwordx16
        float a = vals[v];
        #pragma unroll
        for (int o = 0; o < 16; o++) acc[o] = fmaf(wv[o], a, acc[o]);
      }
    }
  }
  size_t cvb = ((size_t)(b * 144 + g * 16)) * PLANE_A + p;
  #pragma unroll
  for (int o = 0; o < 16; o++) cv[cvb + o * PLANE_A] = acc[o];
}

// ===== depthwise 3x3 pad=1, fused input BN+ReLU + fused output stats =====
template<bool AFF>
__global__ __launch_bounds__(256) void k_dwconv(const float* __restrict__ in,
    const float* __restrict__ w, const float* __restrict__ isc, const float* __restrict__ ish,
    float* __restrict__ out, float* __restrict__ psum, float* __restrict__ psq, int C) {
  int blk = blockIdx.x, tid = threadIdx.x;
  int t = blk * 256 + tid;
  int j = t % HH; int r = t / HH; int i = r % HH; r /= HH; int c = r % C; int b = r / C;
  float s  = AFF ? isc[c] : 1.f;
  float h2 = AFF ? ish[c] : 0.f;
  const float* ip = in + ((size_t)(b * C + c)) * PLANE_A;
  float acc = 0.f;
  #pragma unroll
  for (int ky = 0; ky < 3; ky++) {
    int ii = i + ky - 1;
    if ((unsigned)ii >= (unsigned)HH) continue;
    #pragma unroll
    for (int kx = 0; kx < 3; kx++) {
      int jj = j + kx - 1;
      if ((unsigned)jj >= (unsigned)HH) continue;
      float v = ip[ii * HH + jj];
      if (AFF) v = fmaxf(fmaf(v, s, h2), 0.f);
      acc = fmaf(w[c * 9 + ky * 3 + kx], v, acc);
    }
  }
  out[t] = acc;
  float sv = acc, qv = acc * acc;
  #pragma unroll
  for (int off = 32; off > 0; off >>= 1) { sv += __shfl_down(sv, off); qv += __shfl_down(qv, off); }
  __shared__ float red[4][2];
  int wave = tid >> 6, lane = tid & 63;
  if (lane == 0) { red[wave][0] = sv; red[wave][1] = qv; }
  __syncthreads();
  if (tid == 0) {
    float S = red[0][0] + red[1][0] + red[2][0] + red[3][0];
    float Q = red[0][1] + red[1][1] + red[2][1] + red[3][1];
    int chunk = blk % 36; int rr = blk / 36; int c2 = rr % C; int b2 = rr / C;
    psum[c2 * 72 + b2 * 36 + chunk] = S;
    psq [c2 * 72 + b2 * 36 + chunk] = Q;
  }
}

// ===== pointwise conv: no LDS, scalar weights, 18 outputs/thread =====
// grid (72, 10): x = position block (256 pos), y = output group (18 outputs)
template<int K>
__global__ __launch_bounds__(256) void k_pwconv(const float* __restrict__ in,
    const float* __restrict__ sc, const float* __restrict__ sh,
    const float* __restrict__ w, float* __restrict__ out,
    float* __restrict__ psum, float* __restrict__ psq) {
  int tid = threadIdx.x;
  int p = blockIdx.x * 256 + tid;
  int b = p / PLANE_A, pp = p - b * PLANE_A;
  int obase = blockIdx.y * 18;
  float acc[18];
  #pragma unroll
  for (int o = 0; o < 18; o++) acc[o] = 0.f;
  #pragma unroll 1
  for (int c = 0; c < K; c++) {
    float v = fmaxf(fmaf(in[((size_t)(b * K + c)) * PLANE_A + pp], sc[c], sh[c]), 0.f);
    const float* wc = w + c;                        // w[o*K + c], uniform per o
    #pragma unroll
    for (int o = 0; o < 18; o++)
      acc[o] = fmaf(wc[(obase + o) * K], v, acc[o]);
  }
  #pragma unroll
  for (int o = 0; o < 18; o++)
    out[((size_t)(b * 180 + obase + o)) * PLANE_A + pp] = acc[o];
  // fused stats
  __shared__ float rs[4][18], rq[4][18];
  int wave = tid >> 6, lane = tid & 63;
  #pragma unroll
  for (int o = 0; o < 18; o++) {
    float s = acc[o], q = acc[o] * acc[o];
    #pragma unroll
    for (int off = 32; off > 0; off >>= 1) { s += __shfl_down(s, off); q += __shfl_down(q, off); }
    if (lane == 0) { rs[wave][o] = s; rq[wave][o] = q; }
  }
  __syncthreads();
  if (tid < 18)
    psum[(obase + tid) * 72 + blockIdx.x] = rs[0][tid] + rs[1][tid] + rs[2][tid] + rs[3][tid];
  else if (tid < 36) {
    int o = tid - 18;
    psq[(obase + o) * 72 + blockIdx.x] = rq[0][o] + rq[1][o] + rq[2][o] + rq[3][o];
  }
}

// ===== final: 1x1 conv 180->9 + softmax + expectation, scalar weights =====
__global__ __launch_bounds__(256) void k_final(const float* __restrict__ in,
    const float* __restrict__ sc, const float* __restrict__ sh,
    const float* __restrict__ w, float* __restrict__ out) {
  int tid = threadIdx.x;
  int t = blockIdx.x * 256 + tid;
  int b = t / PLANE_A, p = t - b * PLANE_A;
  float acc[9];
  #pragma unroll
  for (int o = 0; o < 9; o++) acc[o] = 0.f;
  #pragma unroll 1
  for (int c = 0; c < 180; c++) {
    float v = fmaxf(fmaf(in[((size_t)(b * 180 + c)) * PLANE_A + p], sc[c], sh[c]), 0.f);
    #pragma unroll
    for (int o = 0; o < 9; o++) acc[o] = fmaf(w[o * 180 + c], v, acc[o]);
  }
  float m = acc[0];
  #pragma unroll
  for (int o = 1; o < 9; o++) m = fmaxf(m, acc[o]);
  float se = 0.f, num = 0.f;
  #pragma unroll
  for (int o = 0; o < 9; o++) {
    float e = expf(acc[o] - m);
    se += e;
    num += (float)(o - 4) * e;
  }
  out[t] = num / se;
}

extern "C" void kernel_launch(void* const* d_in, const int* in_sizes, int n_in,
                              void* d_out, int out_size, void* d_ws, size_t ws_size,
                              hipStream_t stream) {
  const float* x    = (const float*)d_in[0];
  const float* fw0  = (const float*)d_in[1];
  const float* fg0  = (const float*)d_in[2];
  const float* fb0  = (const float*)d_in[3];
  const float* fw   = (const float*)d_in[4];
  const float* fg   = (const float*)d_in[5];
  const float* fb   = (const float*)d_in[6];
  const float* bcw  = (const float*)d_in[7];
  const float* a0dw = (const float*)d_in[8];
  const float* a0dg = (const float*)d_in[9];
  const float* a0db = (const float*)d_in[10];
  const float* a0pw = (const float*)d_in[11];
  const float* a0pg = (const float*)d_in[12];
  const float* a0pb = (const float*)d_in[13];
  const float* amdw = (const float*)d_in[14];
  const float* amdg = (const float*)d_in[15];
  const float* amdb = (const float*)d_in[16];
  const float* ampw = (const float*)d_in[17];
  const float* ampg = (const float*)d_in[18];
  const float* ampb = (const float*)d_in[19];
  const float* ldw  = (const float*)d_in[20];
  const float* ldg  = (const float*)d_in[21];
  const float* ldb  = (const float*)d_in[22];
  const float* lpw  = (const float*)d_in[23];
  float* outp = (float*)d_out;

  float* FA    = (float*)d_ws;
  float* FB    = FA + (size_t)BB * 7 * PLANE_F;
  float* CV    = FB + (size_t)BB * 7 * PLANE_F;
  float* GA    = CV + (size_t)BB * 144 * PLANE_A;
  float* GB    = GA + (size_t)BB * 180 * PLANE_A;
  float* PSUM  = GB + (size_t)BB * 180 * PLANE_A;
  float* PSQ   = PSUM + 180 * 288;
  float* SC    = PSQ + 180 * 288;
  float* SH    = SC + 180;
  float* WT    = SH + 180;                           // 144*567 = 81648 floats

  const float invNbig = 1.0f / (float)(BB * PLANE_F);
  const float invNsmall = 1.0f / (float)(BB * PLANE_A);

  // weight pre-shuffle for BuildCost (independent of data path)
  k_wprep<<<(144 * 567 + 255) / 256, 256, 0, stream>>>(bcw, WT);

  // feature extraction (SAI layout), stats fused into conv blocks
  k_featconv0<<<NBLK_FEAT, 256, 0, stream>>>(x, fw0, FA, PSUM, PSQ);
  k_bnfinal<<<7, 256, 0, stream>>>(PSUM, PSQ, fg0, fb0, SC, SH, NBLK_FEAT, invNbig);

  float* cur = FA; float* nxt = FB;
  for (int i = 0; i < 6; i++) {
    k_featconv4<<<NBLK_FEAT, 256, 0, stream>>>(cur, fw + i * 441, SC, SH, nxt, PSUM, PSQ);
    k_bnfinal<<<7, 256, 0, stream>>>(PSUM, PSQ, fg + i * 7, fb + i * 7, SC, SH, NBLK_FEAT, invNbig);
    float* tmp = cur; cur = nxt; nxt = tmp;
  }

  // BuildCost (SGPR weights, no LDS)
  k_buildcost<<<dim3(36, 9, 2), 256, 0, stream>>>(cur, SC, SH, WT, CV);

  // aggregation (stats fused everywhere)
  k_dwconv<false><<<BB * 144 * 36, 256, 0, stream>>>(CV, a0dw, nullptr, nullptr, GA, PSUM, PSQ, 144);
  k_bnfinal<<<144, 256, 0, stream>>>(PSUM, PSQ, a0dg, a0db, SC, SH, 72, invNsmall);
  k_pwconv<144><<<dim3(72, 10), 256, 0, stream>>>(GA, SC, SH, a0pw, GB, PSUM, PSQ);
  k_bnfinal<<<180, 256, 0, stream>>>(PSUM, PSQ, a0pg, a0pb, SC, SH, 72, invNsmall);

  for (int m = 0; m < 4; m++) {
    k_dwconv<true><<<BB * 180 * 36, 256, 0, stream>>>(GB, amdw + m * 1620, SC, SH, GA, PSUM, PSQ, 180);
    k_bnfinal<<<180, 256, 0, stream>>>(PSUM, PSQ, amdg + m * 180, amdb + m * 180, SC, SH, 72, invNsmall);
    k_pwconv<180><<<dim3(72, 10), 256, 0, stream>>>(GA, SC, SH, ampw + m * 32400, GB, PSUM, PSQ);
    k_bnfinal<<<180, 256, 0, stream>>>(PSUM, PSQ, ampg + m * 180, ampb + m * 180, SC, SH, 72, invNsmall);
  }

  k_dwconv<true><<<BB * 180 * 36, 256, 0, stream>>>(GB, ldw, SC, SH, GA, PSUM, PSQ, 180);
  k_bnfinal<<<180, 256, 0, stream>>>(PSUM, PSQ, ldg, ldb, SC, SH, 72, invNsmall);

  k_final<<<72, 256, 0, stream>>>(GA, SC, SH, lpw, outp);
}

// Round 6
// 886.529 us; speedup vs baseline: 6.1635x; 1.5599x over previous
//
#include <hip/hip_runtime.h>

#define ANG 9
#define HH 96
#define BB 2
#define PLANE_F (81*HH*HH)  // 746496 per channel (81 views x 96x96)
#define PLANE_A (HH*HH)     // 9216
#define NBLK_FEAT 1458      // BB*81*9 blocks (each: 256 threads, 4-row strips)

// ===== generic BN-final: reduce per-block partials -> scale/shift =====
__global__ __launch_bounds__(256) void k_bnfinal(const float* __restrict__ psum,
    const float* __restrict__ psq, const float* __restrict__ g, const float* __restrict__ bbias,
    float* __restrict__ sc, float* __restrict__ sh, int NB, float invN) {
  int c = blockIdx.x, tid = threadIdx.x;
  float s = 0.f, q = 0.f;
  for (int k = tid; k < NB; k += 256) { s += psum[c * NB + k]; q += psq[c * NB + k]; }
  __shared__ float ss[256], qq[256];
  ss[tid] = s; qq[tid] = q;
  __syncthreads();
  for (int st = 128; st > 0; st >>= 1) {
    if (tid < st) { ss[tid] += ss[tid + st]; qq[tid] += qq[tid + st]; }
    __syncthreads();
  }
  if (tid == 0) {
    float mean = ss[0] * invN;
    float var = fmaxf(qq[0] * invN - mean * mean, 0.f);
    float scale = g[c] / sqrtf(var + 1e-5f);
    sc[c] = scale; sh[c] = bbias[c] - mean * scale;
  }
}

// ===== weight pre-shuffle for BuildCost: WT[((g*7+c)*81 + u*9+v)*16 + o] =====
__global__ __launch_bounds__(256) void k_wprep(const float* __restrict__ w, float* __restrict__ wt) {
  int k = blockIdx.x * 256 + threadIdx.x;
  if (k >= 144 * 567) return;
  int o = k & 15; int rest = k >> 4;
  int r81 = rest % 81; int gc = rest / 81;
  int c = gc % 7, g = gc / 7;
  wt[k] = w[((g * 16 + o) * 7 + c) * 81 + r81];
}

// ===== feature conv0: 1->7 from raw x, branchless clamped window, fused stats =====
__global__ __launch_bounds__(256) void k_featconv0(const float* __restrict__ x,
    const float* __restrict__ w, float* __restrict__ out,
    float* __restrict__ psum, float* __restrict__ psq) {
  int blk = blockIdx.x, tid = threadIdx.x;
  int view = blk / 9, q = blk % 9;
  int b = view / 81, uv = view % 81;
  int u = uv / 9, v = uv % 9;
  int widx = q * 256 + tid;
  int j = widx % HH, i0 = (widx / HH) * 4;
  const float* bx = x + (size_t)b * PLANE_F + (u * HH) * 864 + v * HH;
  int off[6][3]; float m[6][3];
  #pragma unroll
  for (int r6 = 0; r6 < 6; r6++) {
    int ii = i0 + r6 - 1;
    float mi = ((unsigned)ii < 96u) ? 1.f : 0.f;
    int iic = min(max(ii, 0), 95);
    #pragma unroll
    for (int dx = 0; dx < 3; dx++) {
      int jj = j + dx - 1;
      float mj = ((unsigned)jj < 96u) ? 1.f : 0.f;
      int jjc = min(max(jj, 0), 95);
      off[r6][dx] = iic * 864 + jjc;
      m[r6][dx] = mi * mj;
    }
  }
  float win[6][3];
  #pragma unroll
  for (int r6 = 0; r6 < 6; r6++)
    #pragma unroll
    for (int dx = 0; dx < 3; dx++)
      win[r6][dx] = bx[off[r6][dx]] * m[r6][dx];
  float acc[4][7];
  #pragma unroll
  for (int px = 0; px < 4; px++)
    #pragma unroll
    for (int o = 0; o < 7; o++) acc[px][o] = 0.f;
  #pragma unroll
  for (int o = 0; o < 7; o++) {
    const float* wc = w + o * 9;
    #pragma unroll
    for (int ky = 0; ky < 3; ky++)
      #pragma unroll
      for (int kx = 0; kx < 3; kx++) {
        float wv = wc[ky * 3 + kx];
        #pragma unroll
        for (int px = 0; px < 4; px++)
          acc[px][o] = fmaf(win[px + ky][kx], wv, acc[px][o]);
      }
  }
  #pragma unroll
  for (int o = 0; o < 7; o++) {
    float* op = out + ((size_t)(b * 7 + o)) * PLANE_F + uv * PLANE_A + i0 * HH + j;
    #pragma unroll
    for (int px = 0; px < 4; px++) op[px * HH] = acc[px][o];
  }
  float sv[7], qv[7];
  #pragma unroll
  for (int o = 0; o < 7; o++) {
    sv[o] = acc[0][o] + acc[1][o] + acc[2][o] + acc[3][o];
    qv[o] = acc[0][o]*acc[0][o] + acc[1][o]*acc[1][o] + acc[2][o]*acc[2][o] + acc[3][o]*acc[3][o];
  }
  #pragma unroll
  for (int off2 = 32; off2 > 0; off2 >>= 1)
    #pragma unroll
    for (int o = 0; o < 7; o++) { sv[o] += __shfl_down(sv[o], off2); qv[o] += __shfl_down(qv[o], off2); }
  __shared__ float red[4][14];
  int wave = tid >> 6, lane = tid & 63;
  if (lane == 0) {
    #pragma unroll
    for (int o = 0; o < 7; o++) { red[wave][o] = sv[o]; red[wave][7 + o] = qv[o]; }
  }
  __syncthreads();
  if (tid < 14) {
    float t4 = red[0][tid] + red[1][tid] + red[2][tid] + red[3][tid];
    if (tid < 7) psum[tid * NBLK_FEAT + blk] = t4;
    else         psq[(tid - 7) * NBLK_FEAT + blk] = t4;
  }
}

// ===== feature conv: 7->7, branchless clamped window, fused BN+ReLU + stats =====
__global__ __launch_bounds__(256) void k_featconv4(const float* __restrict__ in,
    const float* __restrict__ w, const float* __restrict__ sc, const float* __restrict__ sh,
    float* __restrict__ out, float* __restrict__ psum, float* __restrict__ psq) {
  int blk = blockIdx.x, tid = threadIdx.x;
  int view = blk / 9, q = blk % 9;
  int b = view / 81, uv = view % 81;
  int widx = q * 256 + tid;
  int j = widx % HH, i0 = (widx / HH) * 4;
  int off[6][3]; float m[6][3];
  #pragma unroll
  for (int r6 = 0; r6 < 6; r6++) {
    int ii = i0 + r6 - 1;
    float mi = ((unsigned)ii < 96u) ? 1.f : 0.f;
    int iic = min(max(ii, 0), 95);
    #pragma unroll
    for (int dx = 0; dx < 3; dx++) {
      int jj = j + dx - 1;
      float mj = ((unsigned)jj < 96u) ? 1.f : 0.f;
      int jjc = min(max(jj, 0), 95);
      off[r6][dx] = iic * HH + jjc;
      m[r6][dx] = mi * mj;
    }
  }
  float acc[4][7];
  #pragma unroll
  for (int px = 0; px < 4; px++)
    #pragma unroll
    for (int o = 0; o < 7; o++) acc[px][o] = 0.f;
  #pragma unroll 1
  for (int c = 0; c < 7; c++) {
    const float* ip = in + ((size_t)(b * 7 + c)) * PLANE_F + uv * PLANE_A;
    float s = sc[c], h2 = sh[c];
    float win[6][3];
    #pragma unroll
    for (int r6 = 0; r6 < 6; r6++)
      #pragma unroll
      for (int dx = 0; dx < 3; dx++) {
        float vv = ip[off[r6][dx]];
        win[r6][dx] = fmaxf(fmaf(vv, s, h2), 0.f) * m[r6][dx];
      }
    #pragma unroll
    for (int o = 0; o < 7; o++) {
      const float* wc = w + (o * 7 + c) * 9;
      #pragma unroll
      for (int ky = 0; ky < 3; ky++)
        #pragma unroll
        for (int kx = 0; kx < 3; kx++) {
          float wv = wc[ky * 3 + kx];
          #pragma unroll
          for (int px = 0; px < 4; px++)
            acc[px][o] = fmaf(win[px + ky][kx], wv, acc[px][o]);
        }
    }
  }
  #pragma unroll
  for (int o = 0; o < 7; o++) {
    float* op = out + ((size_t)(b * 7 + o)) * PLANE_F + uv * PLANE_A + i0 * HH + j;
    #pragma unroll
    for (int px = 0; px < 4; px++) op[px * HH] = acc[px][o];
  }
  float sv[7], qv[7];
  #pragma unroll
  for (int o = 0; o < 7; o++) {
    sv[o] = acc[0][o] + acc[1][o] + acc[2][o] + acc[3][o];
    qv[o] = acc[0][o]*acc[0][o] + acc[1][o]*acc[1][o] + acc[2][o]*acc[2][o] + acc[3][o]*acc[3][o];
  }
  #pragma unroll
  for (int off2 = 32; off2 > 0; off2 >>= 1)
    #pragma unroll
    for (int o = 0; o < 7; o++) { sv[o] += __shfl_down(sv[o], off2); qv[o] += __shfl_down(qv[o], off2); }
  __shared__ float red[4][14];
  int wave = tid >> 6, lane = tid & 63;
  if (lane == 0) {
    #pragma unroll
    for (int o = 0; o < 7; o++) { red[wave][o] = sv[o]; red[wave][7 + o] = qv[o]; }
  }
  __syncthreads();
  if (tid < 14) {
    float t4 = red[0][tid] + red[1][tid] + red[2][tid] + red[3][tid];
    if (tid < 7) psum[tid * NBLK_FEAT + blk] = t4;
    else         psq[(tid - 7) * NBLK_FEAT + blk] = t4;
  }
}

// ===== BuildCost helper: branchless clamped 9-tap load =====
__device__ __forceinline__ void bc_load(const float* __restrict__ F, int b, int c, int u,
    int d, int i, int j, float* raw, float* msk) {
  const float* Fc = F + ((size_t)(b * 7 + c)) * PLANE_F + (u * 9) * PLANE_A;
  int ii = i + d * (4 - u);
  float mi = ((unsigned)ii < 96u) ? 1.f : 0.f;
  int iic = min(max(ii, 0), 95);
  const float* Frow = Fc + iic * HH;
  #pragma unroll
  for (int v = 0; v < 9; v++) {
    int jj = j + d * (4 - v);
    float mj = ((unsigned)jj < 96u) ? 1.f : 0.f;
    int jjc = min(max(jj, 0), 95);
    raw[v] = Frow[v * PLANE_A + jjc];
    msk[v] = mi * mj;
  }
}

// ===== BuildCost: 8-o split, SGPR weights, prefetched branchless loads =====
// grid (18, 36, 2): x = gg (g*2+half, fastest for L3 reuse), y = pos block, z = b
__global__ __launch_bounds__(256) void k_buildcost(const float* __restrict__ F,
    const float* __restrict__ sc, const float* __restrict__ sh,
    const float* __restrict__ wt, float* __restrict__ cv) {
  int gg = blockIdx.x, b = blockIdx.z, tid = threadIdx.x;
  int g = gg >> 1, half = gg & 1;
  int d = g - 4;
  bool flip = d > 0;
  int p = blockIdx.y * 256 + tid;
  int i = p / HH, j = p % HH;
  float acc[8];
  #pragma unroll
  for (int o = 0; o < 8; o++) acc[o] = 0.f;
  float raw[9], msk[9];
  bc_load(F, b, 0, 0, d, i, j, raw, msk);
  #pragma unroll 1
  for (int cu = 0; cu < 63; cu++) {
    int c = cu / 9, u = cu - c * 9;
    float cr[9], cm[9];
    #pragma unroll
    for (int v = 0; v < 9; v++) { cr[v] = raw[v]; cm[v] = msk[v]; }
    if (cu + 1 < 63) {
      int cn = (cu + 1) / 9, un = (cu + 1) - cn * 9;
      bc_load(F, b, cn, un, d, i, j, raw, msk);
    }
    float s = sc[c], h2 = sh[c];
    int uw = flip ? 8 - u : u;
    const float* wbase = wt + ((size_t)((g * 7 + c) * 81 + uw * 9)) * 16 + half * 8;
    #pragma unroll
    for (int v = 0; v < 9; v++) {
      float a = fmaxf(fmaf(cr[v], s, h2), 0.f) * cm[v];
      int vw = flip ? 8 - v : v;
      const float* wp = wbase + vw * 16;            // uniform -> s_load
      #pragma unroll
      for (int o = 0; o < 8; o++) acc[o] = fmaf(wp[o], a, acc[o]);
    }
  }
  size_t cvb = ((size_t)(b * 144 + g * 16 + half * 8)) * PLANE_A + p;
  #pragma unroll
  for (int o = 0; o < 8; o++) cv[cvb + o * PLANE_A] = acc[o];
}

// ===== depthwise 3x3 pad=1, fused input BN+ReLU + fused output stats =====
template<bool AFF>
__global__ __launch_bounds__(256) void k_dwconv(const float* __restrict__ in,
    const float* __restrict__ w, const float* __restrict__ isc, const float* __restrict__ ish,
    float* __restrict__ out, float* __restrict__ psum, float* __restrict__ psq, int C) {
  int blk = blockIdx.x, tid = threadIdx.x;
  int t = blk * 256 + tid;
  int j = t % HH; int r = t / HH; int i = r % HH; r /= HH; int c = r % C; int b = r / C;
  float s  = AFF ? isc[c] : 1.f;
  float h2 = AFF ? ish[c] : 0.f;
  const float* ip = in + ((size_t)(b * C + c)) * PLANE_A;
  float acc = 0.f;
  #pragma unroll
  for (int ky = 0; ky < 3; ky++) {
    int ii = i + ky - 1;
    if ((unsigned)ii >= (unsigned)HH) continue;
    #pragma unroll
    for (int kx = 0; kx < 3; kx++) {
      int jj = j + kx - 1;
      if ((unsigned)jj >= (unsigned)HH) continue;
      float v = ip[ii * HH + jj];
      if (AFF) v = fmaxf(fmaf(v, s, h2), 0.f);
      acc = fmaf(w[c * 9 + ky * 3 + kx], v, acc);
    }
  }
  out[t] = acc;
  float sv = acc, qv = acc * acc;
  #pragma unroll
  for (int off = 32; off > 0; off >>= 1) { sv += __shfl_down(sv, off); qv += __shfl_down(qv, off); }
  __shared__ float red[4][2];
  int wave = tid >> 6, lane = tid & 63;
  if (lane == 0) { red[wave][0] = sv; red[wave][1] = qv; }
  __syncthreads();
  if (tid == 0) {
    float S = red[0][0] + red[1][0] + red[2][0] + red[3][0];
    float Q = red[0][1] + red[1][1] + red[2][1] + red[3][1];
    int chunk = blk % 36; int rr = blk / 36; int c2 = rr % C; int b2 = rr / C;
    psum[c2 * 72 + b2 * 36 + chunk] = S;
    psq [c2 * 72 + b2 * 36 + chunk] = Q;
  }
}

// ===== pointwise conv: 12 outputs/thread, unroll-4 prefetch, o-fastest grid =====
// grid (15, 72): x = output group (12 outputs), y = position block
template<int K>
__global__ __launch_bounds__(256) void k_pwconv(const float* __restrict__ in,
    const float* __restrict__ sc, const float* __restrict__ sh,
    const float* __restrict__ w, float* __restrict__ out,
    float* __restrict__ psum, float* __restrict__ psq) {
  int tid = threadIdx.x;
  int posblk = blockIdx.y;
  int p = posblk * 256 + tid;
  int b = p / PLANE_A, pp = p - b * PLANE_A;
  int obase = blockIdx.x * 12;
  float acc[12];
  #pragma unroll
  for (int o = 0; o < 12; o++) acc[o] = 0.f;
  const float* ib = in + (size_t)b * K * PLANE_A + pp;
  float xn[4];
  #pragma unroll
  for (int q2 = 0; q2 < 4; q2++) xn[q2] = ib[(size_t)q2 * PLANE_A];
  #pragma unroll 1
  for (int c0 = 0; c0 < K; c0 += 4) {
    float xv[4];
    #pragma unroll
    for (int q2 = 0; q2 < 4; q2++) xv[q2] = xn[q2];
    if (c0 + 4 < K) {
      #pragma unroll
      for (int q2 = 0; q2 < 4; q2++) xn[q2] = ib[(size_t)(c0 + 4 + q2) * PLANE_A];
    }
    #pragma unroll
    for (int q2 = 0; q2 < 4; q2++) {
      int c = c0 + q2;
      float v = fmaxf(fmaf(xv[q2], sc[c], sh[c]), 0.f);
      const float* wc = w + c;
      #pragma unroll
      for (int o = 0; o < 12; o++)
        acc[o] = fmaf(wc[(size_t)(obase + o) * K], v, acc[o]);
    }
  }
  #pragma unroll
  for (int o = 0; o < 12; o++)
    out[((size_t)(b * 180 + obase + o)) * PLANE_A + pp] = acc[o];
  __shared__ float rs[4][12], rq[4][12];
  int wave = tid >> 6, lane = tid & 63;
  #pragma unroll
  for (int o = 0; o < 12; o++) {
    float s = acc[o], q = acc[o] * acc[o];
    #pragma unroll
    for (int off = 32; off > 0; off >>= 1) { s += __shfl_down(s, off); q += __shfl_down(q, off); }
    if (lane == 0) { rs[wave][o] = s; rq[wave][o] = q; }
  }
  __syncthreads();
  if (tid < 12)
    psum[(obase + tid) * 72 + posblk] = rs[0][tid] + rs[1][tid] + rs[2][tid] + rs[3][tid];
  else if (tid < 24) {
    int o = tid - 12;
    psq[(obase + o) * 72 + posblk] = rq[0][o] + rq[1][o] + rq[2][o] + rq[3][o];
  }
}

// ===== final: 1x1 conv 180->9 + softmax + expectation, unroll-4 prefetch =====
__global__ __launch_bounds__(256) void k_final(const float* __restrict__ in,
    const float* __restrict__ sc, const float* __restrict__ sh,
    const float* __restrict__ w, float* __restrict__ out) {
  int tid = threadIdx.x;
  int t = blockIdx.x * 256 + tid;
  int b = t / PLANE_A, p = t - b * PLANE_A;
  const float* ib = in + (size_t)b * 180 * PLANE_A + p;
  float acc[9];
  #pragma unroll
  for (int o = 0; o < 9; o++) acc[o] = 0.f;
  float xn[4];
  #pragma unroll
  for (int q2 = 0; q2 < 4; q2++) xn[q2] = ib[(size_t)q2 * PLANE_A];
  #pragma unroll 1
  for (int c0 = 0; c0 < 180; c0 += 4) {
    float xv[4];
    #pragma unroll
    for (int q2 = 0; q2 < 4; q2++) xv[q2] = xn[q2];
    if (c0 + 4 < 180) {
      #pragma unroll
      for (int q2 = 0; q2 < 4; q2++) xn[q2] = ib[(size_t)(c0 + 4 + q2) * PLANE_A];
    }
    #pragma unroll
    for (int q2 = 0; q2 < 4; q2++) {
      int c = c0 + q2;
      float v = fmaxf(fmaf(xv[q2], sc[c], sh[c]), 0.f);
      #pragma unroll
      for (int o = 0; o < 9; o++) acc[o] = fmaf(w[o * 180 + c], v, acc[o]);
    }
  }
  float m = acc[0];
  #pragma unroll
  for (int o = 1; o < 9; o++) m = fmaxf(m, acc[o]);
  float se = 0.f, num = 0.f;
  #pragma unroll
  for (int o = 0; o < 9; o++) {
    float e = expf(acc[o] - m);
    se += e;
    num += (float)(o - 4) * e;
  }
  out[t] = num / se;
}

extern "C" void kernel_launch(void* const* d_in, const int* in_sizes, int n_in,
                              void* d_out, int out_size, void* d_ws, size_t ws_size,
                              hipStream_t stream) {
  const float* x    = (const float*)d_in[0];
  const float* fw0  = (const float*)d_in[1];
  const float* fg0  = (const float*)d_in[2];
  const float* fb0  = (const float*)d_in[3];
  const float* fw   = (const float*)d_in[4];
  const float* fg   = (const float*)d_in[5];
  const float* fb   = (const float*)d_in[6];
  const float* bcw  = (const float*)d_in[7];
  const float* a0dw = (const float*)d_in[8];
  const float* a0dg = (const float*)d_in[9];
  const float* a0db = (const float*)d_in[10];
  const float* a0pw = (const float*)d_in[11];
  const float* a0pg = (const float*)d_in[12];
  const float* a0pb = (const float*)d_in[13];
  const float* amdw = (const float*)d_in[14];
  const float* amdg = (const float*)d_in[15];
  const float* amdb = (const float*)d_in[16];
  const float* ampw = (const float*)d_in[17];
  const float* ampg = (const float*)d_in[18];
  const float* ampb = (const float*)d_in[19];
  const float* ldw  = (const float*)d_in[20];
  const float* ldg  = (const float*)d_in[21];
  const float* ldb  = (const float*)d_in[22];
  const float* lpw  = (const float*)d_in[23];
  float* outp = (float*)d_out;

  float* FA    = (float*)d_ws;
  float* FB    = FA + (size_t)BB * 7 * PLANE_F;
  float* CV    = FB + (size_t)BB * 7 * PLANE_F;
  float* GA    = CV + (size_t)BB * 144 * PLANE_A;
  float* GB    = GA + (size_t)BB * 180 * PLANE_A;
  float* PSUM  = GB + (size_t)BB * 180 * PLANE_A;
  float* PSQ   = PSUM + 180 * 288;
  float* SC    = PSQ + 180 * 288;
  float* SH    = SC + 180;
  float* WT    = SH + 180;                           // 144*567 = 81648 floats

  const float invNbig = 1.0f / (float)(BB * PLANE_F);
  const float invNsmall = 1.0f / (float)(BB * PLANE_A);

  // weight pre-shuffle for BuildCost (independent of data path)
  k_wprep<<<(144 * 567 + 255) / 256, 256, 0, stream>>>(bcw, WT);

  // feature extraction (SAI layout), stats fused into conv blocks
  k_featconv0<<<NBLK_FEAT, 256, 0, stream>>>(x, fw0, FA, PSUM, PSQ);
  k_bnfinal<<<7, 256, 0, stream>>>(PSUM, PSQ, fg0, fb0, SC, SH, NBLK_FEAT, invNbig);

  float* cur = FA; float* nxt = FB;
  for (int i = 0; i < 6; i++) {
    k_featconv4<<<NBLK_FEAT, 256, 0, stream>>>(cur, fw + i * 441, SC, SH, nxt, PSUM, PSQ);
    k_bnfinal<<<7, 256, 0, stream>>>(PSUM, PSQ, fg + i * 7, fb + i * 7, SC, SH, NBLK_FEAT, invNbig);
    float* tmp = cur; cur = nxt; nxt = tmp;
  }

  // BuildCost (SGPR weights, branchless prefetched loads, gg-fastest grid)
  k_buildcost<<<dim3(18, 36, 2), 256, 0, stream>>>(cur, SC, SH, WT, CV);

  // aggregation (stats fused everywhere)
  k_dwconv<false><<<BB * 144 * 36, 256, 0, stream>>>(CV, a0dw, nullptr, nullptr, GA, PSUM, PSQ, 144);
  k_bnfinal<<<144, 256, 0, stream>>>(PSUM, PSQ, a0dg, a0db, SC, SH, 72, invNsmall);
  k_pwconv<144><<<dim3(15, 72), 256, 0, stream>>>(GA, SC, SH, a0pw, GB, PSUM, PSQ);
  k_bnfinal<<<180, 256, 0, stream>>>(PSUM, PSQ, a0pg, a0pb, SC, SH, 72, invNsmall);

  for (int m = 0; m < 4; m++) {
    k_dwconv<true><<<BB * 180 * 36, 256, 0, stream>>>(GB, amdw + m * 1620, SC, SH, GA, PSUM, PSQ, 180);
    k_bnfinal<<<180, 256, 0, stream>>>(PSUM, PSQ, amdg + m * 180, amdb + m * 180, SC, SH, 72, invNsmall);
    k_pwconv<180><<<dim3(15, 72), 256, 0, stream>>>(GA, SC, SH, ampw + m * 32400, GB, PSUM, PSQ);
    k_bnfinal<<<180, 256, 0, stream>>>(PSUM, PSQ, ampg + m * 180, ampb + m * 180, SC, SH, 72, invNsmall);
  }

  k_dwconv<true><<<BB * 180 * 36, 256, 0, stream>>>(GB, ldw, SC, SH, GA, PSUM, PSQ, 180);
  k_bnfinal<<<180, 256, 0, stream>>>(PSUM, PSQ, ldg, ldb, SC, SH, 72, invNsmall);

  k_final<<<72, 256, 0, stream>>>(GA, SC, SH, lpw, outp);
}